// Round 15
// baseline (412.954 us; speedup 1.0000x reference)
//
#include <hip/hip_runtime.h>
#include <math.h>

// Factorized GCN: A_hat = D^-1/2 (A+I) D^-1/2. All aggregations are
// prescale(rows by dinv) -> pure gather-sum over CSR cols -> postscale by dinv.
// CSR rows RANK-PERMUTED by class c=i&7 (fill's col lines owned by one XCD);
// node-indexed rows[i]=(rs,re). hA (prescaled h1) AND g (aggregated S) are
// BF16 -> aggH's compulsory FETCH floor (8 XCD x footprint) is halved and its
// write + gemmz's read are halved. fp32 accumulation everywhere; bf16 only on
// stored/gathered operands (measured r14: h1-quant alone -> absmax 7.6e-6).
// aggH is quarter-wave (16 lanes x 16B = 256B bf16 row): 16 rows in flight.

#define CHUNK 2048

__device__ __forceinline__ int rankof(int i, int nq, int nr) {
  int c = i & 7;
  return c * nq + min(c, nr) + (i >> 3);
}
__device__ __forceinline__ unsigned int f2bf(float f) {   // RNE
  unsigned int u = __float_as_uint(f);
  return ((u + 0x7fff + ((u >> 16) & 1)) >> 16);
}
__device__ __forceinline__ float bflo(unsigned int u) { return __uint_as_float(u << 16); }
__device__ __forceinline__ float bfhi(unsigned int u) { return __uint_as_float(u & 0xffff0000u); }
__device__ __forceinline__ void acc8(float4& p, float4& q, uint4 v) {
  p.x += bflo(v.x); p.y += bfhi(v.x); p.z += bflo(v.y); p.w += bfhi(v.y);
  q.x += bflo(v.z); q.y += bfhi(v.z); q.z += bflo(v.w); q.w += bfhi(v.w);
}
__device__ __forceinline__ void acc8w(float4& p, float4& q, uint4 v, float w) {
  p.x = fmaf(bflo(v.x), w, p.x); p.y = fmaf(bfhi(v.x), w, p.y);
  p.z = fmaf(bflo(v.y), w, p.z); p.w = fmaf(bfhi(v.y), w, p.w);
  q.x = fmaf(bflo(v.z), w, q.x); q.y = fmaf(bfhi(v.z), w, q.y);
  q.z = fmaf(bflo(v.w), w, q.z); q.w = fmaf(bfhi(v.w), w, q.w);
}

// ---------------- setup kernels ----------------

__global__ void deg_kernel(const int* __restrict__ dst, int* cnt_rank,
                           int E, int nq, int nr) {
  int e = blockIdx.x * blockDim.x + threadIdx.x;
  if (e < E) atomicAdd(&cnt_rank[rankof(dst[e], nq, nr)], 1);
}

__global__ void dinv_bsum_pad_kernel(const int* __restrict__ cnt_rank,
                                     float* __restrict__ dinv, int* bsum,
                                     const float* __restrict__ x,
                                     float* __restrict__ xp, int N, int nq, int nr) {
  __shared__ int s[256];
  int t = threadIdx.x;
  int gid = blockIdx.x * 256 + t;
  s[t] = (gid < N) ? cnt_rank[gid] : 0;     // scan basis: rank-order, coalesced
  if (gid < N) {
    int c = cnt_rank[rankof(gid, nq, nr)];  // this node's in-degree
    float di = 1.0f / sqrtf((float)c + 1.0f);
    dinv[gid] = di;
    const float* xr = x + (size_t)gid * 9;
    float* xo = xp + (size_t)gid * 16;
    *(float4*)(xo + 0)  = make_float4(xr[0] * di, xr[1] * di, xr[2] * di, xr[3] * di);
    *(float4*)(xo + 4)  = make_float4(xr[4] * di, xr[5] * di, xr[6] * di, xr[7] * di);
    *(float4*)(xo + 8)  = make_float4(xr[8] * di, 0.0f, 0.0f, 0.0f);
    *(float4*)(xo + 12) = make_float4(0.0f, 0.0f, 0.0f, 0.0f);
  }
  __syncthreads();
  for (int off = 128; off > 0; off >>= 1) {
    if (t < off) s[t] += s[t + off];
    __syncthreads();
  }
  if (t == 0) bsum[blockIdx.x] = s[0];
}

// Scan over RANK space; emits rank-indexed cursor (fill) and NODE-indexed
// rows[i]=(rs,re). Block 0 computes v = W3@lin_w, c0 = b3.lin_w + lin_b.
__global__ void rowptr_vc0_kernel(const int* __restrict__ indeg, const int* __restrict__ bsum,
                                  int2* __restrict__ rows, int* cursor, int N, int E,
                                  int nq, int nr,
                                  const float* __restrict__ W3, const float* __restrict__ b3,
                                  const float* __restrict__ lin_w, const float* __restrict__ lin_b,
                                  float* v, float* c0) {
  __shared__ int ps[256];
  __shared__ int s[256];
  int t = threadIdx.x;
  int pref = 0;
  for (int q = t; q < blockIdx.x; q += 256) pref += bsum[q];
  ps[t] = pref;
  __syncthreads();
  for (int off = 128; off > 0; off >>= 1) {
    if (t < off) ps[t] += ps[t + off];
    __syncthreads();
  }
  int base = ps[0];
  int r = blockIdx.x * 256 + t;
  int val = (r < N) ? indeg[r] : 0;
  s[t] = val;
  __syncthreads();
  for (int off = 1; off < 256; off <<= 1) {
    int x = (t >= off) ? s[t - off] : 0;
    __syncthreads();
    s[t] += x;
    __syncthreads();
  }
  int excl = s[t] - val + base;
  if (r < N) {
    cursor[r] = excl;                       // rank-indexed fill cursor
    int c = 0;                              // invert rank -> node id
#pragma unroll
    for (int cc = 1; cc < 8; ++cc) {
      int b = cc * nq + min(cc, nr);
      if (r >= b) c = cc;
    }
    int iinv = ((r - (c * nq + min(c, nr))) << 3) | c;
    rows[iinv] = make_int2(excl, excl + val);  // node-indexed (scattered, once)
  }
  if (blockIdx.x == 0) {
    if (t < 128) {
      float sv = 0.0f;
      for (int c = 0; c < 128; ++c) sv = fmaf(W3[t * 128 + c], lin_w[c], sv);
      v[t] = sv;
    } else if (t == 128) {
      float sv = 0.0f;
      for (int c = 0; c < 128; ++c) sv = fmaf(b3[c], lin_w[c], sv);
      c0[0] = sv + lin_b[0];
    }
  }
}

__global__ __launch_bounds__(256) void fill_part_kernel(const int* __restrict__ src,
                                                        const int* __restrict__ dst,
                                                        int* cursor, int* __restrict__ col,
                                                        int E, int nq, int nr) {
  int sub = blockIdx.x & 7;
  int base = (blockIdx.x >> 3) * CHUNK;
#pragma unroll
  for (int j = 0; j < CHUNK / 256; ++j) {
    int e = base + j * 256 + threadIdx.x;
    if (e < E) {
      int d = dst[e];
      if ((d & 7) == sub) {
        int p = atomicAdd(&cursor[rankof(d, nq, nr)], 1);
        col[p] = src[e];
      }
    }
  }
}

// ---------------- layer 1 fused: xa = dinv_i * sum(xp), hA = bf16(dinv_i * relu(xa@W1+b1)) ----------------
// Per-thread gather, x4 edge unroll (12 aligned 16B gathers in flight).

__global__ __launch_bounds__(256) void agg9_gemm1_kernel(const float* __restrict__ xp,
    const float* __restrict__ dinv, const int2* __restrict__ rows,
    const int* __restrict__ col, const float* __restrict__ W1,
    const float* __restrict__ b1, unsigned short* __restrict__ hA, int N) {
  __shared__ float sW[9 * 128];
  __shared__ float sx[256 * 9];
  __shared__ float sdi[256];           // per-row dinv for the GEMV-phase prescale
  int tid = threadIdx.x;
  for (int q = tid; q < 9 * 128; q += 256) sW[q] = W1[q];
  int i = blockIdx.x * 256 + tid;
  float4 A0, A1, A2, B0, B1, B2;
  A0 = A1 = A2 = B0 = B1 = B2 = make_float4(0.f, 0.f, 0.f, 0.f);
  float di = 0.0f;
  if (i < N) {
    di = dinv[i];
    const float4* xi = (const float4*)(xp + (size_t)i * 16);
    A0 = xi[0]; A1 = xi[1]; A2 = xi[2];   // self term: weight 1 in prescaled domain
    int2 rw = rows[i];
    int rs = rw.x, re = rw.y;
    int e = rs;
    for (; e + 4 <= re; e += 4) {        // x4 unroll: 12 independent 16B gathers in flight
      int c0 = __builtin_nontemporal_load(&col[e]);
      int c1 = __builtin_nontemporal_load(&col[e + 1]);
      int c2 = __builtin_nontemporal_load(&col[e + 2]);
      int c3 = __builtin_nontemporal_load(&col[e + 3]);
      const float4* q0 = (const float4*)(xp + (size_t)c0 * 16);
      const float4* q1 = (const float4*)(xp + (size_t)c1 * 16);
      const float4* q2 = (const float4*)(xp + (size_t)c2 * 16);
      const float4* q3 = (const float4*)(xp + (size_t)c3 * 16);
      float4 r0 = q0[0], r1 = q0[1], r2 = q0[2];
      float4 u0 = q1[0], u1 = q1[1], u2 = q1[2];
      float4 v0 = q2[0], v1 = q2[1], v2 = q2[2];
      float4 w0 = q3[0], w1 = q3[1], w2 = q3[2];
      A0.x += r0.x; A0.y += r0.y; A0.z += r0.z; A0.w += r0.w;
      A1.x += r1.x; A1.y += r1.y; A1.z += r1.z; A1.w += r1.w;
      A2.x += r2.x;
      B0.x += u0.x; B0.y += u0.y; B0.z += u0.z; B0.w += u0.w;
      B1.x += u1.x; B1.y += u1.y; B1.z += u1.z; B1.w += u1.w;
      B2.x += u2.x;
      A0.x += v0.x; A0.y += v0.y; A0.z += v0.z; A0.w += v0.w;
      A1.x += v1.x; A1.y += v1.y; A1.z += v1.z; A1.w += v1.w;
      A2.x += v2.x;
      B0.x += w0.x; B0.y += w0.y; B0.z += w0.z; B0.w += w0.w;
      B1.x += w1.x; B1.y += w1.y; B1.z += w1.z; B1.w += w1.w;
      B2.x += w2.x;
    }
    for (; e + 2 <= re; e += 2) {
      int c0 = __builtin_nontemporal_load(&col[e]);
      int c1 = __builtin_nontemporal_load(&col[e + 1]);
      const float4* q0 = (const float4*)(xp + (size_t)c0 * 16);
      const float4* q1 = (const float4*)(xp + (size_t)c1 * 16);
      float4 r0 = q0[0], r1 = q0[1], r2 = q0[2];
      float4 u0 = q1[0], u1 = q1[1], u2 = q1[2];
      A0.x += r0.x; A0.y += r0.y; A0.z += r0.z; A0.w += r0.w;
      A1.x += r1.x; A1.y += r1.y; A1.z += r1.z; A1.w += r1.w;
      A2.x += r2.x;
      B0.x += u0.x; B0.y += u0.y; B0.z += u0.z; B0.w += u0.w;
      B1.x += u1.x; B1.y += u1.y; B1.z += u1.z; B1.w += u1.w;
      B2.x += u2.x;
    }
    if (e < re) {
      int c0 = __builtin_nontemporal_load(&col[e]);
      const float4* q0 = (const float4*)(xp + (size_t)c0 * 16);
      float4 r0 = q0[0], r1 = q0[1], r2 = q0[2];
      A0.x += r0.x; A0.y += r0.y; A0.z += r0.z; A0.w += r0.w;
      A1.x += r1.x; A1.y += r1.y; A1.z += r1.z; A1.w += r1.w;
      A2.x += r2.x;
    }
  }
  sdi[tid] = di;
  float* so = sx + tid * 9;            // stride 9: worst 2-way alias (free)
  so[0] = (A0.x + B0.x) * di; so[1] = (A0.y + B0.y) * di; so[2] = (A0.z + B0.z) * di;
  so[3] = (A0.w + B0.w) * di; so[4] = (A1.x + B1.x) * di; so[5] = (A1.y + B1.y) * di;
  so[6] = (A1.z + B1.z) * di; so[7] = (A1.w + B1.w) * di; so[8] = (A2.x + B2.x) * di;
  __syncthreads();
  // GEMV phase: thread owns TWO adjacent output columns -> one packed 4B store.
  int c2i = tid & 63, rsub = tid >> 6;   // 64 col-pairs x 4 row-slots
  float wA[9], wB[9];
#pragma unroll
  for (int f = 0; f < 9; ++f) {
    wA[f] = sW[f * 128 + 2 * c2i];
    wB[f] = sW[f * 128 + 2 * c2i + 1];
  }
  float biasA = b1[2 * c2i], biasB = b1[2 * c2i + 1];
  int base = blockIdx.x * 256;
  for (int j = 0; j < 64; ++j) {
    int rl = j * 4 + rsub;             // wave-uniform -> sx reads broadcast
    int row = base + rl;
    if (row >= N) break;               // wave-uniform break
    float sA = biasA, sB = biasB;
#pragma unroll
    for (int f = 0; f < 9; ++f) {
      float xv = sx[rl * 9 + f];
      sA = fmaf(xv, wA[f], sA);
      sB = fmaf(xv, wB[f], sB);
    }
    float d = sdi[rl];
    unsigned int pk = f2bf(fmaxf(sA, 0.0f) * d) | (f2bf(fmaxf(sB, 0.0f) * d) << 16);
    *(unsigned int*)(hA + (size_t)row * 128 + 2 * c2i) = pk;
  }
}

// ---------------- layer 2 aggregation: S = (A+I)-sum of prescaled-h1 rows ----------------
// Quarter-wave: 16 lanes x uint4 (16B) = one full 256B bf16 row; 4-deep unroll
// -> 16 rows in flight per wave. bf16 in, fp32 acc, bf16 out.

__global__ __launch_bounds__(256) void aggH_kernel(const unsigned short* __restrict__ h,
    const int2* __restrict__ rows, const int* __restrict__ col,
    unsigned short* __restrict__ g, int N) {
  int wave = threadIdx.x >> 6;
  int lane = threadIdx.x & 63;
  int q4 = lane >> 4;                  // quarter 0..3
  int l16 = lane & 15;
  int i = blockIdx.x * 4 + wave;
  if (i >= N) return;                  // wave-uniform exit
  uint4 sp = *((const uint4*)(h + (size_t)i * 128) + l16);
  float m = (q4 == 0) ? 1.0f : 0.0f;   // self counted once
  float4 A0 = make_float4(0.f, 0.f, 0.f, 0.f), A1 = A0, B0 = A0, B1 = A0;
  float4 C0 = A0, C1 = A0, D0 = A0, D1 = A0;
  acc8w(A0, A1, sp, m);
  int2 rw = rows[i];
  int rs = rw.x, re = rw.y;
  int e = rs;
  for (; e + 16 <= re; e += 16) {      // 16 edges/iter, 4 gathers in flight per quarter
    int c0 = __builtin_nontemporal_load(&col[e + q4]);
    int c1 = __builtin_nontemporal_load(&col[e + 4 + q4]);
    int c2 = __builtin_nontemporal_load(&col[e + 8 + q4]);
    int c3 = __builtin_nontemporal_load(&col[e + 12 + q4]);
    uint4 p0 = *((const uint4*)(h + (size_t)c0 * 128) + l16);
    uint4 p1 = *((const uint4*)(h + (size_t)c1 * 128) + l16);
    uint4 p2 = *((const uint4*)(h + (size_t)c2 * 128) + l16);
    uint4 p3 = *((const uint4*)(h + (size_t)c3 * 128) + l16);
    acc8(A0, A1, p0); acc8(B0, B1, p1); acc8(C0, C1, p2); acc8(D0, D1, p3);
  }
  for (; e + 4 <= re; e += 4) {
    int c0 = __builtin_nontemporal_load(&col[e + q4]);
    uint4 p0 = *((const uint4*)(h + (size_t)c0 * 128) + l16);
    acc8(C0, C1, p0);
  }
  if (e < re) {                        // 1-3 leftover edges: mask by weight
    int idx = e + q4;
    int c0 = __builtin_nontemporal_load(&col[min(idx, re - 1)]);
    uint4 p0 = *((const uint4*)(h + (size_t)c0 * 128) + l16);
    float w = (idx < re) ? 1.0f : 0.0f;
    acc8w(D0, D1, p0, w);
  }
  float4 s0 = make_float4((A0.x + B0.x) + (C0.x + D0.x), (A0.y + B0.y) + (C0.y + D0.y),
                          (A0.z + B0.z) + (C0.z + D0.z), (A0.w + B0.w) + (C0.w + D0.w));
  float4 s1 = make_float4((A1.x + B1.x) + (C1.x + D1.x), (A1.y + B1.y) + (C1.y + D1.y),
                          (A1.z + B1.z) + (C1.z + D1.z), (A1.w + B1.w) + (C1.w + D1.w));
#pragma unroll
  for (int mk = 16; mk <= 32; mk <<= 1) {   // reduce across quarters (lane bits 4,5)
    s0.x += __shfl_xor(s0.x, mk, 64); s0.y += __shfl_xor(s0.y, mk, 64);
    s0.z += __shfl_xor(s0.z, mk, 64); s0.w += __shfl_xor(s0.w, mk, 64);
    s1.x += __shfl_xor(s1.x, mk, 64); s1.y += __shfl_xor(s1.y, mk, 64);
    s1.z += __shfl_xor(s1.z, mk, 64); s1.w += __shfl_xor(s1.w, mk, 64);
  }
  if (q4 == 0) {                       // lanes 0..15 store packed bf16 row (256B)
    uint4 o;
    o.x = f2bf(s0.x) | (f2bf(s0.y) << 16);
    o.y = f2bf(s0.z) | (f2bf(s0.w) << 16);
    o.z = f2bf(s1.x) | (f2bf(s1.y) << 16);
    o.w = f2bf(s1.z) | (f2bf(s1.w) << 16);
    *((uint4*)(g + (size_t)i * 128) + l16) = o;
  }
}

// ---------------- fused layer-2/3 head: zd = dinv .* (relu(dinv.*(S@W2) + b2) @ v) ----------------
// S (g) is bf16: staging unpacks uint4 (8 bf16) -> Hs fp32.

__global__ __launch_bounds__(256, 4) void gemmz_kernel(const unsigned short* __restrict__ g,
    const float* __restrict__ W2, const float* __restrict__ dinv,
    const float* __restrict__ b2, const float* __restrict__ v,
    float* __restrict__ zd, int N) {
  __shared__ float Hs[32 * 132];   // [k][row], stride 132
  __shared__ float Ws[32 * 128];   // [k][col]; reused as reduce scratch after
  int tid = threadIdx.x;
  int rb = blockIdx.x * 128;
  int tr = tid >> 4, tc = tid & 15;   // 16x16 threads; 8 rows x 8 cols each
  float acc[8][8];
#pragma unroll
  for (int r = 0; r < 8; ++r)
#pragma unroll
    for (int c = 0; c < 8; ++c) acc[r][c] = 0.0f;

  for (int kc = 0; kc < 128; kc += 32) {
#pragma unroll
    for (int j = 0; j < 2; ++j) {      // stage Hs: 512 uint4 (8 bf16 each)
      int q = tid + j * 256;
      int row = q >> 2;
      int seg = q & 3;
      uint4 vv = make_uint4(0u, 0u, 0u, 0u);
      int grow = rb + row;
      if (grow < N) vv = *((const uint4*)(g + (size_t)grow * 128 + kc) + seg);
      int kk = seg * 8;
      Hs[(kk + 0) * 132 + row] = bflo(vv.x); Hs[(kk + 1) * 132 + row] = bfhi(vv.x);
      Hs[(kk + 2) * 132 + row] = bflo(vv.y); Hs[(kk + 3) * 132 + row] = bfhi(vv.y);
      Hs[(kk + 4) * 132 + row] = bflo(vv.z); Hs[(kk + 5) * 132 + row] = bfhi(vv.z);
      Hs[(kk + 6) * 132 + row] = bflo(vv.w); Hs[(kk + 7) * 132 + row] = bfhi(vv.w);
    }
#pragma unroll
    for (int j = 0; j < 4; ++j) {      // stage Ws (fp32 weights)
      int q = tid + j * 256;
      int kr = q >> 5;
      int c4 = (q & 31) * 4;
      *(float4*)&Ws[kr * 128 + c4] = *(const float4*)&W2[(size_t)(kc + kr) * 128 + c4];
    }
    __syncthreads();
#pragma unroll 4
    for (int kk = 0; kk < 32; ++kk) {
      float4 h0 = *(const float4*)&Hs[kk * 132 + tr * 8];
      float4 h1 = *(const float4*)&Hs[kk * 132 + tr * 8 + 4];
      float4 w0 = *(const float4*)&Ws[kk * 128 + tc * 8];
      float4 w1 = *(const float4*)&Ws[kk * 128 + tc * 8 + 4];
      float av[8] = {h0.x, h0.y, h0.z, h0.w, h1.x, h1.y, h1.z, h1.w};
      float bv[8] = {w0.x, w0.y, w0.z, w0.w, w1.x, w1.y, w1.z, w1.w};
#pragma unroll
      for (int r = 0; r < 8; ++r)
#pragma unroll
        for (int c = 0; c < 8; ++c) acc[r][c] = fmaf(av[r], bv[c], acc[r][c]);
    }
    __syncthreads();
  }
  // epilogue: t = dinv_row * acc; p_row = sum_c relu(t + b2_c) * v_c; reduce over tc
  float4 ba = *((const float4*)b2 + tc * 2);
  float4 bb = *((const float4*)b2 + tc * 2 + 1);
  float4 va = *((const float4*)v + tc * 2);
  float4 vb = *((const float4*)v + tc * 2 + 1);
  float bc[8] = {ba.x, ba.y, ba.z, ba.w, bb.x, bb.y, bb.z, bb.w};
  float vc[8] = {va.x, va.y, va.z, va.w, vb.x, vb.y, vb.z, vb.w};
  float* red = Ws;                     // safe: k-loop ended with __syncthreads()
#pragma unroll
  for (int r = 0; r < 8; ++r) {
    int row = rb + tr * 8 + r;
    float p = 0.0f;
    if (row < N) {
      float dr = dinv[row];
#pragma unroll
      for (int c = 0; c < 8; ++c)
        p += fmaxf(fmaf(dr, acc[r][c], bc[c]), 0.0f) * vc[c];
    }
    red[(tr * 8 + r) * 17 + tc] = p;
  }
  __syncthreads();
  if (tid < 128) {
    int row = rb + tid;
    if (row < N) {
      float s = 0.0f;
#pragma unroll
      for (int j = 0; j < 16; ++j) s += red[tid * 17 + j];
      zd[row] = dinv[row] * s;         // prescaled for layer-3 aggregation
    }
  }
}

// ---------------- layer 3 (scalar) aggregation + mean-pool binning ----------------

__global__ void agg1_pool_kernel(const float* __restrict__ zd, const float* __restrict__ dinv,
    const int2* __restrict__ rows, const int* __restrict__ col,
    const int* __restrict__ batch, float* gsum, float* gcnt, int N) {
  __shared__ float lsum[64];
  __shared__ float lcnt[64];
  int t = threadIdx.x;
  if (t < 64) { lsum[t] = 0.0f; lcnt[t] = 0.0f; }
  __syncthreads();
  int i = blockIdx.x * blockDim.x + t;
  if (i < N) {
    float acc = zd[i];                 // self (weight 1 in prescaled domain)
    int2 rw = rows[i];
    int rs = rw.x, re = rw.y;
    int e = rs;
    for (; e + 4 <= re; e += 4) {      // x4 unroll: 4 scalar gathers in flight
      float z0 = zd[col[e]], z1 = zd[col[e + 1]];
      float z2 = zd[col[e + 2]], z3 = zd[col[e + 3]];
      acc += (z0 + z1) + (z2 + z3);
    }
    for (; e < re; ++e) acc += zd[col[e]];
    acc *= dinv[i];
    int gidx = batch[i];
    atomicAdd(&lsum[gidx], acc);
    atomicAdd(&lcnt[gidx], 1.0f);
  }
  __syncthreads();
  if (t < 64) {
    if (lsum[t] != 0.0f) atomicAdd(&gsum[t], lsum[t]);
    if (lcnt[t] != 0.0f) atomicAdd(&gcnt[t], lcnt[t]);
  }
}

__global__ void final_kernel(const float* __restrict__ gsum, const float* __restrict__ gcnt,
                             const float* __restrict__ c0, float* out, int G) {
  int g = threadIdx.x;
  if (g < G) out[g] = gsum[g] / fmaxf(gcnt[g], 1.0f) + c0[0];
}

// ---------------- launch ----------------

extern "C" void kernel_launch(void* const* d_in, const int* in_sizes, int n_in,
                              void* d_out, int out_size, void* d_ws, size_t ws_size,
                              hipStream_t stream) {
  const float* x      = (const float*)d_in[0];
  const int*   eidx   = (const int*)d_in[1];
  const int*   batch  = (const int*)d_in[2];
  const float* W1     = (const float*)d_in[3];
  const float* b1     = (const float*)d_in[4];
  const float* W2     = (const float*)d_in[5];
  const float* b2     = (const float*)d_in[6];
  const float* W3     = (const float*)d_in[7];
  const float* b3     = (const float*)d_in[8];
  const float* lin_w  = (const float*)d_in[9];
  const float* lin_b  = (const float*)d_in[10];
  float* out = (float*)d_out;

  int N = in_sizes[0] / 9;
  int E = in_sizes[1] / 2;
  int G = out_size;
  const int* src = eidx;
  const int* dst = eidx + E;
  int nq = N >> 3, nr = N & 7;         // rank(i) = (i&7)*nq + min(i&7,nr) + (i>>3)

  char* w = (char*)d_ws;
  size_t off = 0;
  auto alloc = [&](size_t bytes) -> void* {
    void* p = w + off;
    off += bytes;
    off = (off + 255) & ~(size_t)255;
    return p;
  };

  int nb = (N + 255) / 256;
  int nchunk = (E + CHUNK - 1) / CHUNK;
  // zero-init region (one memset): cursor (rank-space degree counts), gsum, gcnt
  int*   cursor = (int*)  alloc((size_t)N * 4);        // counts, then fill cursor (rank-indexed)
  float* gsum   = (float*)alloc(64 * 4);
  float* gcnt   = (float*)alloc(64 * 4);
  size_t zspan = off;
  float* dinv   = (float*)alloc((size_t)N * 4);
  int2*  rows   = (int2*) alloc((size_t)N * 8);        // node-indexed (rs,re)
  int*   bsum   = (int*)  alloc((size_t)nb * 4);
  int*   colsrc = (int*)  alloc((size_t)E * 4);        // CSR cols, class-contiguous regions
  unsigned short* hA = (unsigned short*)alloc((size_t)N * 128 * 2);  // prescaled h1, BF16
  unsigned short* g  = (unsigned short*)alloc((size_t)N * 128 * 2);  // xp (Nx16 fp32) first, then S BF16
  float* zd     = (float*)alloc((size_t)N * 4);
  float* v      = (float*)alloc(128 * 4);
  float* c0     = (float*)alloc(4);
  float* xp     = (float*)g;                           // alias: dead before aggH writes g

  hipMemsetAsync(d_ws, 0, zspan, stream);
  deg_kernel<<<(E + 255) / 256, 256, 0, stream>>>(dst, cursor, E, nq, nr);
  dinv_bsum_pad_kernel<<<nb, 256, 0, stream>>>(cursor, dinv, bsum, x, xp, N, nq, nr);
  rowptr_vc0_kernel<<<nb, 256, 0, stream>>>(cursor, bsum, rows, cursor, N, E, nq, nr,
                                            W3, b3, lin_w, lin_b, v, c0);
  fill_part_kernel<<<nchunk * 8, 256, 0, stream>>>(src, dst, cursor, colsrc, E, nq, nr);
  agg9_gemm1_kernel<<<nb, 256, 0, stream>>>(xp, dinv, rows, colsrc, W1, b1, hA, N);
  aggH_kernel<<<(N + 3) / 4, 256, 0, stream>>>(hA, rows, colsrc, g, N);
  gemmz_kernel<<<(N + 127) / 128, 256, 0, stream>>>(g, W2, dinv, b2, v, zd, N);
  agg1_pool_kernel<<<nb, 256, 0, stream>>>(zd, dinv, rows, colsrc, batch, gsum, gcnt, N);
  final_kernel<<<1, 64, 0, stream>>>(gsum, gcnt, c0, out, G);
}

// Round 16
// 405.571 us; speedup vs baseline: 1.0182x; 1.0182x over previous
//
#include <hip/hip_runtime.h>
#include <math.h>

// Factorized GCN: A_hat = D^-1/2 (A+I) D^-1/2. All aggregations are
// prescale(rows by dinv) -> pure gather-sum over CSR cols -> postscale by dinv.
// CSR rows RANK-PERMUTED by class c=i&7 (fill's col lines owned by one XCD);
// node-indexed rows[i]=(rs,re). hA (prescaled h1) AND g (aggregated S) are
// BF16; fp32 accumulation everywhere (r14: h1-quant alone -> absmax 7.6e-6).
// aggH is HALF-WAVE (32 lanes x uint2 = 256B bf16 row, 8 edges/iter): r15's
// quarter-wave (VGPR 40, occ 53%) regressed vs half-wave (VGPR 24, occ 71%) —
// occupancy beats per-wave MLP in this latency-bound gather regime.

#define CHUNK 2048

__device__ __forceinline__ int rankof(int i, int nq, int nr) {
  int c = i & 7;
  return c * nq + min(c, nr) + (i >> 3);
}
__device__ __forceinline__ unsigned int f2bf(float f) {   // RNE
  unsigned int u = __float_as_uint(f);
  return ((u + 0x7fff + ((u >> 16) & 1)) >> 16);
}
__device__ __forceinline__ float bflo(unsigned int u) { return __uint_as_float(u << 16); }
__device__ __forceinline__ float bfhi(unsigned int u) { return __uint_as_float(u & 0xffff0000u); }

// ---------------- setup kernels ----------------

__global__ void deg_kernel(const int* __restrict__ dst, int* cnt_rank,
                           int E, int nq, int nr) {
  int e = blockIdx.x * blockDim.x + threadIdx.x;
  if (e < E) atomicAdd(&cnt_rank[rankof(dst[e], nq, nr)], 1);
}

__global__ void dinv_bsum_pad_kernel(const int* __restrict__ cnt_rank,
                                     float* __restrict__ dinv, int* bsum,
                                     const float* __restrict__ x,
                                     float* __restrict__ xp, int N, int nq, int nr) {
  __shared__ int s[256];
  int t = threadIdx.x;
  int gid = blockIdx.x * 256 + t;
  s[t] = (gid < N) ? cnt_rank[gid] : 0;     // scan basis: rank-order, coalesced
  if (gid < N) {
    int c = cnt_rank[rankof(gid, nq, nr)];  // this node's in-degree
    float di = 1.0f / sqrtf((float)c + 1.0f);
    dinv[gid] = di;
    const float* xr = x + (size_t)gid * 9;
    float* xo = xp + (size_t)gid * 16;
    *(float4*)(xo + 0)  = make_float4(xr[0] * di, xr[1] * di, xr[2] * di, xr[3] * di);
    *(float4*)(xo + 4)  = make_float4(xr[4] * di, xr[5] * di, xr[6] * di, xr[7] * di);
    *(float4*)(xo + 8)  = make_float4(xr[8] * di, 0.0f, 0.0f, 0.0f);
    *(float4*)(xo + 12) = make_float4(0.0f, 0.0f, 0.0f, 0.0f);
  }
  __syncthreads();
  for (int off = 128; off > 0; off >>= 1) {
    if (t < off) s[t] += s[t + off];
    __syncthreads();
  }
  if (t == 0) bsum[blockIdx.x] = s[0];
}

// Scan over RANK space; emits rank-indexed cursor (fill) and NODE-indexed
// rows[i]=(rs,re). Block 0 computes v = W3@lin_w, c0 = b3.lin_w + lin_b.
__global__ void rowptr_vc0_kernel(const int* __restrict__ indeg, const int* __restrict__ bsum,
                                  int2* __restrict__ rows, int* cursor, int N, int E,
                                  int nq, int nr,
                                  const float* __restrict__ W3, const float* __restrict__ b3,
                                  const float* __restrict__ lin_w, const float* __restrict__ lin_b,
                                  float* v, float* c0) {
  __shared__ int ps[256];
  __shared__ int s[256];
  int t = threadIdx.x;
  int pref = 0;
  for (int q = t; q < blockIdx.x; q += 256) pref += bsum[q];
  ps[t] = pref;
  __syncthreads();
  for (int off = 128; off > 0; off >>= 1) {
    if (t < off) ps[t] += ps[t + off];
    __syncthreads();
  }
  int base = ps[0];
  int r = blockIdx.x * 256 + t;
  int val = (r < N) ? indeg[r] : 0;
  s[t] = val;
  __syncthreads();
  for (int off = 1; off < 256; off <<= 1) {
    int x = (t >= off) ? s[t - off] : 0;
    __syncthreads();
    s[t] += x;
    __syncthreads();
  }
  int excl = s[t] - val + base;
  if (r < N) {
    cursor[r] = excl;                       // rank-indexed fill cursor
    int c = 0;                              // invert rank -> node id
#pragma unroll
    for (int cc = 1; cc < 8; ++cc) {
      int b = cc * nq + min(cc, nr);
      if (r >= b) c = cc;
    }
    int iinv = ((r - (c * nq + min(c, nr))) << 3) | c;
    rows[iinv] = make_int2(excl, excl + val);  // node-indexed (scattered, once)
  }
  if (blockIdx.x == 0) {
    if (t < 128) {
      float sv = 0.0f;
      for (int c = 0; c < 128; ++c) sv = fmaf(W3[t * 128 + c], lin_w[c], sv);
      v[t] = sv;
    } else if (t == 128) {
      float sv = 0.0f;
      for (int c = 0; c < 128; ++c) sv = fmaf(b3[c], lin_w[c], sv);
      c0[0] = sv + lin_b[0];
    }
  }
}

__global__ __launch_bounds__(256) void fill_part_kernel(const int* __restrict__ src,
                                                        const int* __restrict__ dst,
                                                        int* cursor, int* __restrict__ col,
                                                        int E, int nq, int nr) {
  int sub = blockIdx.x & 7;
  int base = (blockIdx.x >> 3) * CHUNK;
#pragma unroll
  for (int j = 0; j < CHUNK / 256; ++j) {
    int e = base + j * 256 + threadIdx.x;
    if (e < E) {
      int d = dst[e];
      if ((d & 7) == sub) {
        int p = atomicAdd(&cursor[rankof(d, nq, nr)], 1);
        col[p] = src[e];
      }
    }
  }
}

// ---------------- layer 1 fused: xa = dinv_i * sum(xp), hA = bf16(dinv_i * relu(xa@W1+b1)) ----------------
// Per-thread gather, x4 edge unroll (12 aligned 16B gathers in flight).

__global__ __launch_bounds__(256) void agg9_gemm1_kernel(const float* __restrict__ xp,
    const float* __restrict__ dinv, const int2* __restrict__ rows,
    const int* __restrict__ col, const float* __restrict__ W1,
    const float* __restrict__ b1, unsigned short* __restrict__ hA, int N) {
  __shared__ float sW[9 * 128];
  __shared__ float sx[256 * 9];
  __shared__ float sdi[256];           // per-row dinv for the GEMV-phase prescale
  int tid = threadIdx.x;
  for (int q = tid; q < 9 * 128; q += 256) sW[q] = W1[q];
  int i = blockIdx.x * 256 + tid;
  float4 A0, A1, A2, B0, B1, B2;
  A0 = A1 = A2 = B0 = B1 = B2 = make_float4(0.f, 0.f, 0.f, 0.f);
  float di = 0.0f;
  if (i < N) {
    di = dinv[i];
    const float4* xi = (const float4*)(xp + (size_t)i * 16);
    A0 = xi[0]; A1 = xi[1]; A2 = xi[2];   // self term: weight 1 in prescaled domain
    int2 rw = rows[i];
    int rs = rw.x, re = rw.y;
    int e = rs;
    for (; e + 4 <= re; e += 4) {        // x4 unroll: 12 independent 16B gathers in flight
      int c0 = __builtin_nontemporal_load(&col[e]);
      int c1 = __builtin_nontemporal_load(&col[e + 1]);
      int c2 = __builtin_nontemporal_load(&col[e + 2]);
      int c3 = __builtin_nontemporal_load(&col[e + 3]);
      const float4* q0 = (const float4*)(xp + (size_t)c0 * 16);
      const float4* q1 = (const float4*)(xp + (size_t)c1 * 16);
      const float4* q2 = (const float4*)(xp + (size_t)c2 * 16);
      const float4* q3 = (const float4*)(xp + (size_t)c3 * 16);
      float4 r0 = q0[0], r1 = q0[1], r2 = q0[2];
      float4 u0 = q1[0], u1 = q1[1], u2 = q1[2];
      float4 v0 = q2[0], v1 = q2[1], v2 = q2[2];
      float4 w0 = q3[0], w1 = q3[1], w2 = q3[2];
      A0.x += r0.x; A0.y += r0.y; A0.z += r0.z; A0.w += r0.w;
      A1.x += r1.x; A1.y += r1.y; A1.z += r1.z; A1.w += r1.w;
      A2.x += r2.x;
      B0.x += u0.x; B0.y += u0.y; B0.z += u0.z; B0.w += u0.w;
      B1.x += u1.x; B1.y += u1.y; B1.z += u1.z; B1.w += u1.w;
      B2.x += u2.x;
      A0.x += v0.x; A0.y += v0.y; A0.z += v0.z; A0.w += v0.w;
      A1.x += v1.x; A1.y += v1.y; A1.z += v1.z; A1.w += v1.w;
      A2.x += v2.x;
      B0.x += w0.x; B0.y += w0.y; B0.z += w0.z; B0.w += w0.w;
      B1.x += w1.x; B1.y += w1.y; B1.z += w1.z; B1.w += w1.w;
      B2.x += w2.x;
    }
    for (; e + 2 <= re; e += 2) {
      int c0 = __builtin_nontemporal_load(&col[e]);
      int c1 = __builtin_nontemporal_load(&col[e + 1]);
      const float4* q0 = (const float4*)(xp + (size_t)c0 * 16);
      const float4* q1 = (const float4*)(xp + (size_t)c1 * 16);
      float4 r0 = q0[0], r1 = q0[1], r2 = q0[2];
      float4 u0 = q1[0], u1 = q1[1], u2 = q1[2];
      A0.x += r0.x; A0.y += r0.y; A0.z += r0.z; A0.w += r0.w;
      A1.x += r1.x; A1.y += r1.y; A1.z += r1.z; A1.w += r1.w;
      A2.x += r2.x;
      B0.x += u0.x; B0.y += u0.y; B0.z += u0.z; B0.w += u0.w;
      B1.x += u1.x; B1.y += u1.y; B1.z += u1.z; B1.w += u1.w;
      B2.x += u2.x;
    }
    if (e < re) {
      int c0 = __builtin_nontemporal_load(&col[e]);
      const float4* q0 = (const float4*)(xp + (size_t)c0 * 16);
      float4 r0 = q0[0], r1 = q0[1], r2 = q0[2];
      A0.x += r0.x; A0.y += r0.y; A0.z += r0.z; A0.w += r0.w;
      A1.x += r1.x; A1.y += r1.y; A1.z += r1.z; A1.w += r1.w;
      A2.x += r2.x;
    }
  }
  sdi[tid] = di;
  float* so = sx + tid * 9;            // stride 9: worst 2-way alias (free)
  so[0] = (A0.x + B0.x) * di; so[1] = (A0.y + B0.y) * di; so[2] = (A0.z + B0.z) * di;
  so[3] = (A0.w + B0.w) * di; so[4] = (A1.x + B1.x) * di; so[5] = (A1.y + B1.y) * di;
  so[6] = (A1.z + B1.z) * di; so[7] = (A1.w + B1.w) * di; so[8] = (A2.x + B2.x) * di;
  __syncthreads();
  // GEMV phase: thread owns TWO adjacent output columns -> one packed 4B store.
  int c2i = tid & 63, rsub = tid >> 6;   // 64 col-pairs x 4 row-slots
  float wA[9], wB[9];
#pragma unroll
  for (int f = 0; f < 9; ++f) {
    wA[f] = sW[f * 128 + 2 * c2i];
    wB[f] = sW[f * 128 + 2 * c2i + 1];
  }
  float biasA = b1[2 * c2i], biasB = b1[2 * c2i + 1];
  int base = blockIdx.x * 256;
  for (int j = 0; j < 64; ++j) {
    int rl = j * 4 + rsub;             // wave-uniform -> sx reads broadcast
    int row = base + rl;
    if (row >= N) break;               // wave-uniform break
    float sA = biasA, sB = biasB;
#pragma unroll
    for (int f = 0; f < 9; ++f) {
      float xv = sx[rl * 9 + f];
      sA = fmaf(xv, wA[f], sA);
      sB = fmaf(xv, wB[f], sB);
    }
    float d = sdi[rl];
    unsigned int pk = f2bf(fmaxf(sA, 0.0f) * d) | (f2bf(fmaxf(sB, 0.0f) * d) << 16);
    *(unsigned int*)(hA + (size_t)row * 128 + 2 * c2i) = pk;
  }
}

// ---------------- layer 2 aggregation: S = (A+I)-sum of prescaled-h1 rows ----------------
// Half-wave: 32 lanes x uint2 (8B) = one full 256B bf16 row; 8 edges/iter,
// 4 gathers in flight per half. bf16 in, fp32 acc, bf16 out (packed store).

__global__ __launch_bounds__(256) void aggH_kernel(const unsigned short* __restrict__ h,
    const int2* __restrict__ rows, const int* __restrict__ col,
    unsigned short* __restrict__ g, int N) {
  int wave = threadIdx.x >> 6;
  int lane = threadIdx.x & 63;
  int half = lane >> 5;                // each 32-lane half gathers one full row
  int l32  = lane & 31;
  int i = blockIdx.x * 4 + wave;
  if (i >= N) return;                  // wave-uniform exit
  uint2 sp = *((const uint2*)(h + (size_t)i * 128) + l32);
  float m = half ? 0.0f : 1.0f;        // self counted once (lower half)
  float4 a0 = make_float4(bflo(sp.x) * m, bfhi(sp.x) * m, bflo(sp.y) * m, bfhi(sp.y) * m);
  float4 a1 = make_float4(0.f, 0.f, 0.f, 0.f);
  float4 a2 = make_float4(0.f, 0.f, 0.f, 0.f);
  float4 a3 = make_float4(0.f, 0.f, 0.f, 0.f);
  int2 rw = rows[i];
  int rs = rw.x, re = rw.y;
  int e = rs;
  for (; e + 8 <= re; e += 8) {        // 8 edges/iter, 4 gathers in flight per half
    int c0 = __builtin_nontemporal_load(&col[e + half]);
    int c1 = __builtin_nontemporal_load(&col[e + 2 + half]);
    int c2 = __builtin_nontemporal_load(&col[e + 4 + half]);
    int c3 = __builtin_nontemporal_load(&col[e + 6 + half]);
    uint2 p0 = *((const uint2*)(h + (size_t)c0 * 128) + l32);
    uint2 p1 = *((const uint2*)(h + (size_t)c1 * 128) + l32);
    uint2 p2 = *((const uint2*)(h + (size_t)c2 * 128) + l32);
    uint2 p3 = *((const uint2*)(h + (size_t)c3 * 128) + l32);
    a0.x += bflo(p0.x); a0.y += bfhi(p0.x); a0.z += bflo(p0.y); a0.w += bfhi(p0.y);
    a1.x += bflo(p1.x); a1.y += bfhi(p1.x); a1.z += bflo(p1.y); a1.w += bfhi(p1.y);
    a2.x += bflo(p2.x); a2.y += bfhi(p2.x); a2.z += bflo(p2.y); a2.w += bfhi(p2.y);
    a3.x += bflo(p3.x); a3.y += bfhi(p3.x); a3.z += bflo(p3.y); a3.w += bfhi(p3.y);
  }
  if (e + 4 <= re) {
    int c0 = __builtin_nontemporal_load(&col[e + half]);
    int c1 = __builtin_nontemporal_load(&col[e + 2 + half]);
    uint2 p0 = *((const uint2*)(h + (size_t)c0 * 128) + l32);
    uint2 p1 = *((const uint2*)(h + (size_t)c1 * 128) + l32);
    a0.x += bflo(p0.x); a0.y += bfhi(p0.x); a0.z += bflo(p0.y); a0.w += bfhi(p0.y);
    a1.x += bflo(p1.x); a1.y += bfhi(p1.x); a1.z += bflo(p1.y); a1.w += bfhi(p1.y);
    e += 4;
  }
  if (e + 2 <= re) {
    int c0 = __builtin_nontemporal_load(&col[e + half]);
    uint2 p0 = *((const uint2*)(h + (size_t)c0 * 128) + l32);
    a2.x += bflo(p0.x); a2.y += bfhi(p0.x); a2.z += bflo(p0.y); a2.w += bfhi(p0.y);
    e += 2;
  }
  if (e < re) {                        // odd tail: both halves take 0.5 (exact)
    int c0 = __builtin_nontemporal_load(&col[e]);
    uint2 p0 = *((const uint2*)(h + (size_t)c0 * 128) + l32);
    a3.x = fmaf(bflo(p0.x), 0.5f, a3.x); a3.y = fmaf(bfhi(p0.x), 0.5f, a3.y);
    a3.z = fmaf(bflo(p0.y), 0.5f, a3.z); a3.w = fmaf(bfhi(p0.y), 0.5f, a3.w);
  }
  float4 a = make_float4((a0.x + a1.x) + (a2.x + a3.x), (a0.y + a1.y) + (a2.y + a3.y),
                         (a0.z + a1.z) + (a2.z + a3.z), (a0.w + a1.w) + (a2.w + a3.w));
  a.x += __shfl_down(a.x, 32, 64);     // combine halves -> lanes 0..31 hold full row
  a.y += __shfl_down(a.y, 32, 64);
  a.z += __shfl_down(a.z, 32, 64);
  a.w += __shfl_down(a.w, 32, 64);
  if (half == 0) {                     // lanes 0..31 pack bf16 -> 256B row store
    uint2 o;
    o.x = f2bf(a.x) | (f2bf(a.y) << 16);
    o.y = f2bf(a.z) | (f2bf(a.w) << 16);
    *((uint2*)(g + (size_t)i * 128) + l32) = o;
  }
}

// ---------------- fused layer-2/3 head: zd = dinv .* (relu(dinv.*(S@W2) + b2) @ v) ----------------
// S (g) is bf16: staging unpacks uint4 (8 bf16) -> Hs fp32.

__global__ __launch_bounds__(256, 4) void gemmz_kernel(const unsigned short* __restrict__ g,
    const float* __restrict__ W2, const float* __restrict__ dinv,
    const float* __restrict__ b2, const float* __restrict__ v,
    float* __restrict__ zd, int N) {
  __shared__ float Hs[32 * 132];   // [k][row], stride 132
  __shared__ float Ws[32 * 128];   // [k][col]; reused as reduce scratch after
  int tid = threadIdx.x;
  int rb = blockIdx.x * 128;
  int tr = tid >> 4, tc = tid & 15;   // 16x16 threads; 8 rows x 8 cols each
  float acc[8][8];
#pragma unroll
  for (int r = 0; r < 8; ++r)
#pragma unroll
    for (int c = 0; c < 8; ++c) acc[r][c] = 0.0f;

  for (int kc = 0; kc < 128; kc += 32) {
#pragma unroll
    for (int j = 0; j < 2; ++j) {      // stage Hs: 512 uint4 (8 bf16 each)
      int q = tid + j * 256;
      int row = q >> 2;
      int seg = q & 3;
      uint4 vv = make_uint4(0u, 0u, 0u, 0u);
      int grow = rb + row;
      if (grow < N) vv = *((const uint4*)(g + (size_t)grow * 128 + kc) + seg);
      int kk = seg * 8;
      Hs[(kk + 0) * 132 + row] = bflo(vv.x); Hs[(kk + 1) * 132 + row] = bfhi(vv.x);
      Hs[(kk + 2) * 132 + row] = bflo(vv.y); Hs[(kk + 3) * 132 + row] = bfhi(vv.y);
      Hs[(kk + 4) * 132 + row] = bflo(vv.z); Hs[(kk + 5) * 132 + row] = bfhi(vv.z);
      Hs[(kk + 6) * 132 + row] = bflo(vv.w); Hs[(kk + 7) * 132 + row] = bfhi(vv.w);
    }
#pragma unroll
    for (int j = 0; j < 4; ++j) {      // stage Ws (fp32 weights)
      int q = tid + j * 256;
      int kr = q >> 5;
      int c4 = (q & 31) * 4;
      *(float4*)&Ws[kr * 128 + c4] = *(const float4*)&W2[(size_t)(kc + kr) * 128 + c4];
    }
    __syncthreads();
#pragma unroll 4
    for (int kk = 0; kk < 32; ++kk) {
      float4 h0 = *(const float4*)&Hs[kk * 132 + tr * 8];
      float4 h1 = *(const float4*)&Hs[kk * 132 + tr * 8 + 4];
      float4 w0 = *(const float4*)&Ws[kk * 128 + tc * 8];
      float4 w1 = *(const float4*)&Ws[kk * 128 + tc * 8 + 4];
      float av[8] = {h0.x, h0.y, h0.z, h0.w, h1.x, h1.y, h1.z, h1.w};
      float bv[8] = {w0.x, w0.y, w0.z, w0.w, w1.x, w1.y, w1.z, w1.w};
#pragma unroll
      for (int r = 0; r < 8; ++r)
#pragma unroll
        for (int c = 0; c < 8; ++c) acc[r][c] = fmaf(av[r], bv[c], acc[r][c]);
    }
    __syncthreads();
  }
  // epilogue: t = dinv_row * acc; p_row = sum_c relu(t + b2_c) * v_c; reduce over tc
  float4 ba = *((const float4*)b2 + tc * 2);
  float4 bb = *((const float4*)b2 + tc * 2 + 1);
  float4 va = *((const float4*)v + tc * 2);
  float4 vb = *((const float4*)v + tc * 2 + 1);
  float bc[8] = {ba.x, ba.y, ba.z, ba.w, bb.x, bb.y, bb.z, bb.w};
  float vc[8] = {va.x, va.y, va.z, va.w, vb.x, vb.y, vb.z, vb.w};
  float* red = Ws;                     // safe: k-loop ended with __syncthreads()
#pragma unroll
  for (int r = 0; r < 8; ++r) {
    int row = rb + tr * 8 + r;
    float p = 0.0f;
    if (row < N) {
      float dr = dinv[row];
#pragma unroll
      for (int c = 0; c < 8; ++c)
        p += fmaxf(fmaf(dr, acc[r][c], bc[c]), 0.0f) * vc[c];
    }
    red[(tr * 8 + r) * 17 + tc] = p;
  }
  __syncthreads();
  if (tid < 128) {
    int row = rb + tid;
    if (row < N) {
      float s = 0.0f;
#pragma unroll
      for (int j = 0; j < 16; ++j) s += red[tid * 17 + j];
      zd[row] = dinv[row] * s;         // prescaled for layer-3 aggregation
    }
  }
}

// ---------------- layer 3 (scalar) aggregation + mean-pool binning ----------------

__global__ void agg1_pool_kernel(const float* __restrict__ zd, const float* __restrict__ dinv,
    const int2* __restrict__ rows, const int* __restrict__ col,
    const int* __restrict__ batch, float* gsum, float* gcnt, int N) {
  __shared__ float lsum[64];
  __shared__ float lcnt[64];
  int t = threadIdx.x;
  if (t < 64) { lsum[t] = 0.0f; lcnt[t] = 0.0f; }
  __syncthreads();
  int i = blockIdx.x * blockDim.x + t;
  if (i < N) {
    float acc = zd[i];                 // self (weight 1 in prescaled domain)
    int2 rw = rows[i];
    int rs = rw.x, re = rw.y;
    int e = rs;
    for (; e + 4 <= re; e += 4) {      // x4 unroll: 4 scalar gathers in flight
      float z0 = zd[col[e]], z1 = zd[col[e + 1]];
      float z2 = zd[col[e + 2]], z3 = zd[col[e + 3]];
      acc += (z0 + z1) + (z2 + z3);
    }
    for (; e < re; ++e) acc += zd[col[e]];
    acc *= dinv[i];
    int gidx = batch[i];
    atomicAdd(&lsum[gidx], acc);
    atomicAdd(&lcnt[gidx], 1.0f);
  }
  __syncthreads();
  if (t < 64) {
    if (lsum[t] != 0.0f) atomicAdd(&gsum[t], lsum[t]);
    if (lcnt[t] != 0.0f) atomicAdd(&gcnt[t], lcnt[t]);
  }
}

__global__ void final_kernel(const float* __restrict__ gsum, const float* __restrict__ gcnt,
                             const float* __restrict__ c0, float* out, int G) {
  int g = threadIdx.x;
  if (g < G) out[g] = gsum[g] / fmaxf(gcnt[g], 1.0f) + c0[0];
}

// ---------------- launch ----------------

extern "C" void kernel_launch(void* const* d_in, const int* in_sizes, int n_in,
                              void* d_out, int out_size, void* d_ws, size_t ws_size,
                              hipStream_t stream) {
  const float* x      = (const float*)d_in[0];
  const int*   eidx   = (const int*)d_in[1];
  const int*   batch  = (const int*)d_in[2];
  const float* W1     = (const float*)d_in[3];
  const float* b1     = (const float*)d_in[4];
  const float* W2     = (const float*)d_in[5];
  const float* b2     = (const float*)d_in[6];
  const float* W3     = (const float*)d_in[7];
  const float* b3     = (const float*)d_in[8];
  const float* lin_w  = (const float*)d_in[9];
  const float* lin_b  = (const float*)d_in[10];
  float* out = (float*)d_out;

  int N = in_sizes[0] / 9;
  int E = in_sizes[1] / 2;
  int G = out_size;
  const int* src = eidx;
  const int* dst = eidx + E;
  int nq = N >> 3, nr = N & 7;         // rank(i) = (i&7)*nq + min(i&7,nr) + (i>>3)

  char* w = (char*)d_ws;
  size_t off = 0;
  auto alloc = [&](size_t bytes) -> void* {
    void* p = w + off;
    off += bytes;
    off = (off + 255) & ~(size_t)255;
    return p;
  };

  int nb = (N + 255) / 256;
  int nchunk = (E + CHUNK - 1) / CHUNK;
  // zero-init region (one memset): cursor (rank-space degree counts), gsum, gcnt
  int*   cursor = (int*)  alloc((size_t)N * 4);        // counts, then fill cursor (rank-indexed)
  float* gsum   = (float*)alloc(64 * 4);
  float* gcnt   = (float*)alloc(64 * 4);
  size_t zspan = off;
  float* dinv   = (float*)alloc((size_t)N * 4);
  int2*  rows   = (int2*) alloc((size_t)N * 8);        // node-indexed (rs,re)
  int*   bsum   = (int*)  alloc((size_t)nb * 4);
  int*   colsrc = (int*)  alloc((size_t)E * 4);        // CSR cols, class-contiguous regions
  unsigned short* hA = (unsigned short*)alloc((size_t)N * 128 * 2);  // prescaled h1, BF16
  unsigned short* g  = (unsigned short*)alloc((size_t)N * 128 * 2);  // xp (Nx16 fp32) first, then S BF16
  float* zd     = (float*)alloc((size_t)N * 4);
  float* v      = (float*)alloc(128 * 4);
  float* c0     = (float*)alloc(4);
  float* xp     = (float*)g;                           // alias: dead before aggH writes g

  hipMemsetAsync(d_ws, 0, zspan, stream);
  deg_kernel<<<(E + 255) / 256, 256, 0, stream>>>(dst, cursor, E, nq, nr);
  dinv_bsum_pad_kernel<<<nb, 256, 0, stream>>>(cursor, dinv, bsum, x, xp, N, nq, nr);
  rowptr_vc0_kernel<<<nb, 256, 0, stream>>>(cursor, bsum, rows, cursor, N, E, nq, nr,
                                            W3, b3, lin_w, lin_b, v, c0);
  fill_part_kernel<<<nchunk * 8, 256, 0, stream>>>(src, dst, cursor, colsrc, E, nq, nr);
  agg9_gemm1_kernel<<<nb, 256, 0, stream>>>(xp, dinv, rows, colsrc, W1, b1, hA, N);
  aggH_kernel<<<(N + 3) / 4, 256, 0, stream>>>(hA, rows, colsrc, g, N);
  gemmz_kernel<<<(N + 127) / 128, 256, 0, stream>>>(g, W2, dinv, b2, v, zd, N);
  agg1_pool_kernel<<<nb, 256, 0, stream>>>(zd, dinv, rows, colsrc, batch, gsum, gcnt, N);
  final_kernel<<<1, 64, 0, stream>>>(gsum, gcnt, c0, out, G);
}

// Round 17
// 367.962 us; speedup vs baseline: 1.1223x; 1.1022x over previous
//
#include <hip/hip_runtime.h>
#include <math.h>

// Factorized GCN: A_hat = D^-1/2 (A+I) D^-1/2. All aggregations are
// prescale(rows by dinv) -> pure gather-sum over CSR cols -> postscale by dinv.
// CSR rows RANK-PERMUTED by class c=i&7 (fill's col lines owned by one XCD);
// node-indexed rows[i]=(rs,re). BF16 storage everywhere it's gathered/streamed:
// xp (prescaled x, 32B rows -> 3.2MB = L2-resident/XCD), hA (prescaled h1),
// g (aggregated S). fp32 accumulation everywhere. gemmz uses bf16 MFMA
// (g is already bf16; W2 pre-packed to B-fragment layout, 32KB L2-resident).
// aggH half-wave (r15 quarter-wave lesson: occupancy > per-wave MLP).

#define CHUNK 2048

using short8 = __attribute__((ext_vector_type(8))) short;
using floatx4 = __attribute__((ext_vector_type(4))) float;

__device__ __forceinline__ int rankof(int i, int nq, int nr) {
  int c = i & 7;
  return c * nq + min(c, nr) + (i >> 3);
}
__device__ __forceinline__ unsigned int f2bf(float f) {   // RNE
  unsigned int u = __float_as_uint(f);
  return ((u + 0x7fff + ((u >> 16) & 1)) >> 16);
}
__device__ __forceinline__ float bflo(unsigned int u) { return __uint_as_float(u << 16); }
__device__ __forceinline__ float bfhi(unsigned int u) { return __uint_as_float(u & 0xffff0000u); }

// ---------------- setup kernels ----------------

__global__ void deg_kernel(const int* __restrict__ dst, int* cnt_rank,
                           int E, int nq, int nr) {
  int e = blockIdx.x * blockDim.x + threadIdx.x;
  if (e < E) atomicAdd(&cnt_rank[rankof(dst[e], nq, nr)], 1);
}

// dinv + per-block rank-order sums -> bsum; xp = bf16(dinv_i * x_i), 16 bf16/row (32B)
__global__ void dinv_bsum_pad_kernel(const int* __restrict__ cnt_rank,
                                     float* __restrict__ dinv, int* bsum,
                                     const float* __restrict__ x,
                                     unsigned short* __restrict__ xp, int N, int nq, int nr) {
  __shared__ int s[256];
  int t = threadIdx.x;
  int gid = blockIdx.x * 256 + t;
  s[t] = (gid < N) ? cnt_rank[gid] : 0;     // scan basis: rank-order, coalesced
  if (gid < N) {
    int c = cnt_rank[rankof(gid, nq, nr)];  // this node's in-degree
    float di = 1.0f / sqrtf((float)c + 1.0f);
    dinv[gid] = di;
    const float* xr = x + (size_t)gid * 9;
    unsigned int w0 = f2bf(xr[0] * di) | (f2bf(xr[1] * di) << 16);
    unsigned int w1 = f2bf(xr[2] * di) | (f2bf(xr[3] * di) << 16);
    unsigned int w2 = f2bf(xr[4] * di) | (f2bf(xr[5] * di) << 16);
    unsigned int w3 = f2bf(xr[6] * di) | (f2bf(xr[7] * di) << 16);
    unsigned int w4 = f2bf(xr[8] * di);
    uint4* xo = (uint4*)(xp + (size_t)gid * 16);
    xo[0] = make_uint4(w0, w1, w2, w3);
    xo[1] = make_uint4(w4, 0u, 0u, 0u);
  }
  __syncthreads();
  for (int off = 128; off > 0; off >>= 1) {
    if (t < off) s[t] += s[t + off];
    __syncthreads();
  }
  if (t == 0) bsum[blockIdx.x] = s[0];
}

// Scan over RANK space -> rank-indexed cursor (fill) + NODE-indexed rows[i].
// Block 0: v = W3@lin_w, c0 = b3.lin_w + lin_b; zero g row N (gemmz pad row).
// Blocks 1..8: pack W2 -> bf16 B-fragment layout W2p[ntile][kstep][lane][8].
__global__ void rowptr_vc0_kernel(const int* __restrict__ indeg, const int* __restrict__ bsum,
                                  int2* __restrict__ rows, int* cursor, int N, int E,
                                  int nq, int nr,
                                  const float* __restrict__ W3, const float* __restrict__ b3,
                                  const float* __restrict__ lin_w, const float* __restrict__ lin_b,
                                  const float* __restrict__ W2, unsigned short* __restrict__ W2p,
                                  unsigned short* __restrict__ g,
                                  float* v, float* c0) {
  __shared__ int ps[256];
  __shared__ int s[256];
  int t = threadIdx.x;
  int pref = 0;
  for (int q = t; q < blockIdx.x; q += 256) pref += bsum[q];
  ps[t] = pref;
  __syncthreads();
  for (int off = 128; off > 0; off >>= 1) {
    if (t < off) ps[t] += ps[t + off];
    __syncthreads();
  }
  int base = ps[0];
  int r = blockIdx.x * 256 + t;
  int val = (r < N) ? indeg[r] : 0;
  s[t] = val;
  __syncthreads();
  for (int off = 1; off < 256; off <<= 1) {
    int x = (t >= off) ? s[t - off] : 0;
    __syncthreads();
    s[t] += x;
    __syncthreads();
  }
  int excl = s[t] - val + base;
  if (r < N) {
    cursor[r] = excl;                       // rank-indexed fill cursor
    int c = 0;                              // invert rank -> node id
#pragma unroll
    for (int cc = 1; cc < 8; ++cc) {
      int b = cc * nq + min(cc, nr);
      if (r >= b) c = cc;
    }
    int iinv = ((r - (c * nq + min(c, nr))) << 3) | c;
    rows[iinv] = make_int2(excl, excl + val);  // node-indexed (scattered, once)
  }
  if (blockIdx.x == 0) {
    if (t < 64) ((unsigned int*)g)[(size_t)N * 64 + t] = 0u;  // zero pad row N
    if (t < 128) {
      float sv = 0.0f;
      for (int c = 0; c < 128; ++c) sv = fmaf(W3[t * 128 + c], lin_w[c], sv);
      v[t] = sv;
    } else if (t == 128) {
      float sv = 0.0f;
      for (int c = 0; c < 128; ++c) sv = fmaf(b3[c], lin_w[c], sv);
      c0[0] = sv + lin_b[0];
    }
  } else if (blockIdx.x <= 8) {
    // B-frag pack: lane holds W2[k][n], n = ntile*16 + (lane&15),
    // k = kstep*32 + (lane>>4)*8 + j, j=0..7
    int ntile = blockIdx.x - 1;
    int kstep = t >> 6, lane = t & 63;
    int n = ntile * 16 + (lane & 15);
    int k0 = kstep * 32 + ((lane >> 4) & 3) * 8;
    unsigned int pk[4];
#pragma unroll
    for (int jj = 0; jj < 4; ++jj)
      pk[jj] = f2bf(W2[(size_t)(k0 + 2 * jj) * 128 + n])
             | (f2bf(W2[(size_t)(k0 + 2 * jj + 1) * 128 + n]) << 16);
    *(uint4*)(W2p + (size_t)(((ntile * 4 + kstep) * 64 + lane) * 8)) =
        make_uint4(pk[0], pk[1], pk[2], pk[3]);
  }
}

__global__ __launch_bounds__(256) void fill_part_kernel(const int* __restrict__ src,
                                                        const int* __restrict__ dst,
                                                        int* cursor, int* __restrict__ col,
                                                        int E, int nq, int nr) {
  int sub = blockIdx.x & 7;
  int base = (blockIdx.x >> 3) * CHUNK;
#pragma unroll
  for (int j = 0; j < CHUNK / 256; ++j) {
    int e = base + j * 256 + threadIdx.x;
    if (e < E) {
      int d = dst[e];
      if ((d & 7) == sub) {
        int p = atomicAdd(&cursor[rankof(d, nq, nr)], 1);
        col[p] = src[e];
      }
    }
  }
}

// ---------------- layer 1 fused: xa = dinv_i * sum(xp), hA = bf16(dinv_i * relu(xa@W1+b1)) ----------------
// Per-thread gather over bf16 xp rows (32B, L2-resident footprint), x2 unroll.

__global__ __launch_bounds__(256) void agg9_gemm1_kernel(const unsigned short* __restrict__ xp,
    const float* __restrict__ dinv, const int2* __restrict__ rows,
    const int* __restrict__ col, const float* __restrict__ W1,
    const float* __restrict__ b1, unsigned short* __restrict__ hA, int N) {
  __shared__ float sW[9 * 128];
  __shared__ float sx[256 * 9];
  __shared__ float sdi[256];           // per-row dinv for the GEMV-phase prescale
  int tid = threadIdx.x;
  for (int q = tid; q < 9 * 128; q += 256) sW[q] = W1[q];
  int i = blockIdx.x * 256 + tid;
  float A[9], B[9];
#pragma unroll
  for (int f = 0; f < 9; ++f) { A[f] = 0.0f; B[f] = 0.0f; }
  float di = 0.0f;
  if (i < N) {
    di = dinv[i];
    const unsigned short* xi = xp + (size_t)i * 16;
    uint4 s0 = *(const uint4*)xi;
    unsigned int s1 = *(const unsigned int*)(xi + 8);
    A[0] = bflo(s0.x); A[1] = bfhi(s0.x); A[2] = bflo(s0.y); A[3] = bfhi(s0.y);
    A[4] = bflo(s0.z); A[5] = bfhi(s0.z); A[6] = bflo(s0.w); A[7] = bfhi(s0.w);
    A[8] = bflo(s1);                  // self term (weight 1 in prescaled domain)
    int2 rw = rows[i];
    int rs = rw.x, re = rw.y;
    int e = rs;
    for (; e + 2 <= re; e += 2) {     // x2 unroll: 4 loads in flight, L2-resident
      int c0 = __builtin_nontemporal_load(&col[e]);
      int c1 = __builtin_nontemporal_load(&col[e + 1]);
      const unsigned short* p0 = xp + (size_t)c0 * 16;
      const unsigned short* p1 = xp + (size_t)c1 * 16;
      uint4 q0 = *(const uint4*)p0;
      unsigned int t0 = *(const unsigned int*)(p0 + 8);
      uint4 q1 = *(const uint4*)p1;
      unsigned int t1 = *(const unsigned int*)(p1 + 8);
      A[0] += bflo(q0.x); A[1] += bfhi(q0.x); A[2] += bflo(q0.y); A[3] += bfhi(q0.y);
      A[4] += bflo(q0.z); A[5] += bfhi(q0.z); A[6] += bflo(q0.w); A[7] += bfhi(q0.w);
      A[8] += bflo(t0);
      B[0] += bflo(q1.x); B[1] += bfhi(q1.x); B[2] += bflo(q1.y); B[3] += bfhi(q1.y);
      B[4] += bflo(q1.z); B[5] += bfhi(q1.z); B[6] += bflo(q1.w); B[7] += bfhi(q1.w);
      B[8] += bflo(t1);
    }
    if (e < re) {
      int c0 = __builtin_nontemporal_load(&col[e]);
      const unsigned short* p0 = xp + (size_t)c0 * 16;
      uint4 q0 = *(const uint4*)p0;
      unsigned int t0 = *(const unsigned int*)(p0 + 8);
      A[0] += bflo(q0.x); A[1] += bfhi(q0.x); A[2] += bflo(q0.y); A[3] += bfhi(q0.y);
      A[4] += bflo(q0.z); A[5] += bfhi(q0.z); A[6] += bflo(q0.w); A[7] += bfhi(q0.w);
      A[8] += bflo(t0);
    }
  }
  sdi[tid] = di;
  float* so = sx + tid * 9;            // stride 9: worst 2-way alias (free)
#pragma unroll
  for (int f = 0; f < 9; ++f) so[f] = (A[f] + B[f]) * di;
  __syncthreads();
  // GEMV phase: thread owns TWO adjacent output columns -> one packed 4B store.
  int c2i = tid & 63, rsub = tid >> 6;   // 64 col-pairs x 4 row-slots
  float wA[9], wB[9];
#pragma unroll
  for (int f = 0; f < 9; ++f) {
    wA[f] = sW[f * 128 + 2 * c2i];
    wB[f] = sW[f * 128 + 2 * c2i + 1];
  }
  float biasA = b1[2 * c2i], biasB = b1[2 * c2i + 1];
  int base = blockIdx.x * 256;
  for (int j = 0; j < 64; ++j) {
    int rl = j * 4 + rsub;             // wave-uniform -> sx reads broadcast
    int row = base + rl;
    if (row >= N) break;               // wave-uniform break
    float sA = biasA, sB = biasB;
#pragma unroll
    for (int f = 0; f < 9; ++f) {
      float xv = sx[rl * 9 + f];
      sA = fmaf(xv, wA[f], sA);
      sB = fmaf(xv, wB[f], sB);
    }
    float d = sdi[rl];
    unsigned int pk = f2bf(fmaxf(sA, 0.0f) * d) | (f2bf(fmaxf(sB, 0.0f) * d) << 16);
    *(unsigned int*)(hA + (size_t)row * 128 + 2 * c2i) = pk;
  }
}

// ---------------- layer 2 aggregation: S = (A+I)-sum of prescaled-h1 rows ----------------
// Half-wave: 32 lanes x uint2 (8B) = one full 256B bf16 row; 8 edges/iter.
// [r16: 72.5 us, FETCH = 8 XCD x 25.6 MB compulsory floor]

__global__ __launch_bounds__(256) void aggH_kernel(const unsigned short* __restrict__ h,
    const int2* __restrict__ rows, const int* __restrict__ col,
    unsigned short* __restrict__ g, int N) {
  int wave = threadIdx.x >> 6;
  int lane = threadIdx.x & 63;
  int half = lane >> 5;                // each 32-lane half gathers one full row
  int l32  = lane & 31;
  int i = blockIdx.x * 4 + wave;
  if (i >= N) return;                  // wave-uniform exit
  uint2 sp = *((const uint2*)(h + (size_t)i * 128) + l32);
  float m = half ? 0.0f : 1.0f;        // self counted once (lower half)
  float4 a0 = make_float4(bflo(sp.x) * m, bfhi(sp.x) * m, bflo(sp.y) * m, bfhi(sp.y) * m);
  float4 a1 = make_float4(0.f, 0.f, 0.f, 0.f);
  float4 a2 = make_float4(0.f, 0.f, 0.f, 0.f);
  float4 a3 = make_float4(0.f, 0.f, 0.f, 0.f);
  int2 rw = rows[i];
  int rs = rw.x, re = rw.y;
  int e = rs;
  for (; e + 8 <= re; e += 8) {        // 8 edges/iter, 4 gathers in flight per half
    int c0 = __builtin_nontemporal_load(&col[e + half]);
    int c1 = __builtin_nontemporal_load(&col[e + 2 + half]);
    int c2 = __builtin_nontemporal_load(&col[e + 4 + half]);
    int c3 = __builtin_nontemporal_load(&col[e + 6 + half]);
    uint2 p0 = *((const uint2*)(h + (size_t)c0 * 128) + l32);
    uint2 p1 = *((const uint2*)(h + (size_t)c1 * 128) + l32);
    uint2 p2 = *((const uint2*)(h + (size_t)c2 * 128) + l32);
    uint2 p3 = *((const uint2*)(h + (size_t)c3 * 128) + l32);
    a0.x += bflo(p0.x); a0.y += bfhi(p0.x); a0.z += bflo(p0.y); a0.w += bfhi(p0.y);
    a1.x += bflo(p1.x); a1.y += bfhi(p1.x); a1.z += bflo(p1.y); a1.w += bfhi(p1.y);
    a2.x += bflo(p2.x); a2.y += bfhi(p2.x); a2.z += bflo(p2.y); a2.w += bfhi(p2.y);
    a3.x += bflo(p3.x); a3.y += bfhi(p3.x); a3.z += bflo(p3.y); a3.w += bfhi(p3.y);
  }
  if (e + 4 <= re) {
    int c0 = __builtin_nontemporal_load(&col[e + half]);
    int c1 = __builtin_nontemporal_load(&col[e + 2 + half]);
    uint2 p0 = *((const uint2*)(h + (size_t)c0 * 128) + l32);
    uint2 p1 = *((const uint2*)(h + (size_t)c1 * 128) + l32);
    a0.x += bflo(p0.x); a0.y += bfhi(p0.x); a0.z += bflo(p0.y); a0.w += bfhi(p0.y);
    a1.x += bflo(p1.x); a1.y += bfhi(p1.x); a1.z += bflo(p1.y); a1.w += bfhi(p1.y);
    e += 4;
  }
  if (e + 2 <= re) {
    int c0 = __builtin_nontemporal_load(&col[e + half]);
    uint2 p0 = *((const uint2*)(h + (size_t)c0 * 128) + l32);
    a2.x += bflo(p0.x); a2.y += bfhi(p0.x); a2.z += bflo(p0.y); a2.w += bfhi(p0.y);
    e += 2;
  }
  if (e < re) {                        // odd tail: both halves take 0.5 (exact)
    int c0 = __builtin_nontemporal_load(&col[e]);
    uint2 p0 = *((const uint2*)(h + (size_t)c0 * 128) + l32);
    a3.x = fmaf(bflo(p0.x), 0.5f, a3.x); a3.y = fmaf(bfhi(p0.x), 0.5f, a3.y);
    a3.z = fmaf(bflo(p0.y), 0.5f, a3.z); a3.w = fmaf(bfhi(p0.y), 0.5f, a3.w);
  }
  float4 a = make_float4((a0.x + a1.x) + (a2.x + a3.x), (a0.y + a1.y) + (a2.y + a3.y),
                         (a0.z + a1.z) + (a2.z + a3.z), (a0.w + a1.w) + (a2.w + a3.w));
  a.x += __shfl_down(a.x, 32, 64);     // combine halves -> lanes 0..31 hold full row
  a.y += __shfl_down(a.y, 32, 64);
  a.z += __shfl_down(a.z, 32, 64);
  a.w += __shfl_down(a.w, 32, 64);
  if (half == 0) {                     // lanes 0..31 pack bf16 -> 256B row store
    uint2 o;
    o.x = f2bf(a.x) | (f2bf(a.y) << 16);
    o.y = f2bf(a.z) | (f2bf(a.w) << 16);
    *((uint2*)(g + (size_t)i * 128) + l32) = o;
  }
}

// ---------------- fused layer-2/3 head via bf16 MFMA ----------------
// zd = dinv .* (relu(dinv.*(S@W2) + b2) @ v). S (g) is bf16 rows; W2 pre-packed
// bf16 B-frags. LDS-free, barrier-free: 4 waves/block x 16 rows each.
// A-frag: lane holds S[row = rb16 + (lane&15)][k = kstep*32 + (lane>>4)*8 + j].
// C-frag: col = t*16 + (lane&15), row(within 16) = (lane>>4)*4 + reg.

__global__ __launch_bounds__(256) void gemmz_kernel(const unsigned short* __restrict__ g,
    const unsigned short* __restrict__ W2p, const float* __restrict__ dinv,
    const float* __restrict__ b2, const float* __restrict__ v,
    float* __restrict__ zd, int N) {
  int wave = threadIdx.x >> 6, lane = threadIdx.x & 63;
  int rb16 = blockIdx.x * 64 + wave * 16;       // wave's 16-row window
  int m = lane & 15, quad = lane >> 4;
  int rowA = rb16 + m;
  const unsigned short* gp = g + (size_t)((rowA < N) ? rowA : N) * 128 + quad * 8;
  floatx4 acc[8];
#pragma unroll
  for (int t = 0; t < 8; ++t) acc[t] = (floatx4){0.f, 0.f, 0.f, 0.f};
#pragma unroll
  for (int ks = 0; ks < 4; ++ks) {
    short8 afrag = *(const short8*)(gp + ks * 32);
#pragma unroll
    for (int t = 0; t < 8; ++t) {
      short8 bfrag = *(const short8*)(W2p + (size_t)(((t * 4 + ks) * 64 + lane) * 8));
      acc[t] = __builtin_amdgcn_mfma_f32_16x16x32_bf16(afrag, bfrag, acc[t], 0, 0, 0);
    }
  }
  float b2c[8], vc[8];
#pragma unroll
  for (int t = 0; t < 8; ++t) {
    int ncol = t * 16 + m;
    b2c[t] = b2[ncol];
    vc[t] = v[ncol];
  }
#pragma unroll
  for (int reg = 0; reg < 4; ++reg) {
    int grow = rb16 + quad * 4 + reg;
    float dr = (grow < N) ? dinv[grow] : 0.0f;
    float p = 0.0f;
#pragma unroll
    for (int t = 0; t < 8; ++t)
      p += fmaxf(fmaf(dr, acc[t][reg], b2c[t]), 0.0f) * vc[t];
#pragma unroll
    for (int mk = 1; mk <= 8; mk <<= 1) p += __shfl_xor(p, mk, 64);  // over m (lane&15)
    if (m == 0 && grow < N) zd[grow] = dr * p;   // prescaled for layer-3
  }
}

// ---------------- layer 3 (scalar) aggregation + mean-pool binning ----------------

__global__ void agg1_pool_kernel(const float* __restrict__ zd, const float* __restrict__ dinv,
    const int2* __restrict__ rows, const int* __restrict__ col,
    const int* __restrict__ batch, float* gsum, float* gcnt, int N) {
  __shared__ float lsum[64];
  __shared__ float lcnt[64];
  int t = threadIdx.x;
  if (t < 64) { lsum[t] = 0.0f; lcnt[t] = 0.0f; }
  __syncthreads();
  int i = blockIdx.x * blockDim.x + t;
  if (i < N) {
    float acc = zd[i];                 // self (weight 1 in prescaled domain)
    int2 rw = rows[i];
    int rs = rw.x, re = rw.y;
    int e = rs;
    for (; e + 4 <= re; e += 4) {      // x4 unroll: 4 scalar gathers in flight
      float z0 = zd[col[e]], z1 = zd[col[e + 1]];
      float z2 = zd[col[e + 2]], z3 = zd[col[e + 3]];
      acc += (z0 + z1) + (z2 + z3);
    }
    for (; e < re; ++e) acc += zd[col[e]];
    acc *= dinv[i];
    int gidx = batch[i];
    atomicAdd(&lsum[gidx], acc);
    atomicAdd(&lcnt[gidx], 1.0f);
  }
  __syncthreads();
  if (t < 64) {
    if (lsum[t] != 0.0f) atomicAdd(&gsum[t], lsum[t]);
    if (lcnt[t] != 0.0f) atomicAdd(&gcnt[t], lcnt[t]);
  }
}

__global__ void final_kernel(const float* __restrict__ gsum, const float* __restrict__ gcnt,
                             const float* __restrict__ c0, float* out, int G) {
  int g = threadIdx.x;
  if (g < G) out[g] = gsum[g] / fmaxf(gcnt[g], 1.0f) + c0[0];
}

// ---------------- launch ----------------

extern "C" void kernel_launch(void* const* d_in, const int* in_sizes, int n_in,
                              void* d_out, int out_size, void* d_ws, size_t ws_size,
                              hipStream_t stream) {
  const float* x      = (const float*)d_in[0];
  const int*   eidx   = (const int*)d_in[1];
  const int*   batch  = (const int*)d_in[2];
  const float* W1     = (const float*)d_in[3];
  const float* b1     = (const float*)d_in[4];
  const float* W2     = (const float*)d_in[5];
  const float* b2     = (const float*)d_in[6];
  const float* W3     = (const float*)d_in[7];
  const float* b3     = (const float*)d_in[8];
  const float* lin_w  = (const float*)d_in[9];
  const float* lin_b  = (const float*)d_in[10];
  float* out = (float*)d_out;

  int N = in_sizes[0] / 9;
  int E = in_sizes[1] / 2;
  int G = out_size;
  const int* src = eidx;
  const int* dst = eidx + E;
  int nq = N >> 3, nr = N & 7;         // rank(i) = (i&7)*nq + min(i&7,nr) + (i>>3)

  char* w = (char*)d_ws;
  size_t off = 0;
  auto alloc = [&](size_t bytes) -> void* {
    void* p = w + off;
    off += bytes;
    off = (off + 255) & ~(size_t)255;
    return p;
  };

  int nb = (N + 255) / 256;
  int nchunk = (E + CHUNK - 1) / CHUNK;
  // zero-init region (one memset): cursor (rank-space degree counts), gsum, gcnt
  int*   cursor = (int*)  alloc((size_t)N * 4);        // counts, then fill cursor (rank-indexed)
  float* gsum   = (float*)alloc(64 * 4);
  float* gcnt   = (float*)alloc(64 * 4);
  size_t zspan = off;
  float* dinv   = (float*)alloc((size_t)N * 4);
  int2*  rows   = (int2*) alloc((size_t)N * 8);        // node-indexed (rs,re)
  int*   bsum   = (int*)  alloc((size_t)nb * 4);
  int*   colsrc = (int*)  alloc((size_t)E * 4);        // CSR cols, class-contiguous regions
  unsigned short* hA  = (unsigned short*)alloc((size_t)N * 128 * 2);        // prescaled h1, BF16
  unsigned short* g   = (unsigned short*)alloc((size_t)(N + 1) * 128 * 2);  // xp (Nx16 bf16) first, then S BF16 (+pad row N)
  unsigned short* W2p = (unsigned short*)alloc(8 * 4 * 64 * 8 * 2);         // MFMA B-frag packed W2
  float* zd     = (float*)alloc((size_t)N * 4);
  float* v      = (float*)alloc(128 * 4);
  float* c0     = (float*)alloc(4);
  unsigned short* xp = g;                              // alias: dead before aggH writes g

  hipMemsetAsync(d_ws, 0, zspan, stream);
  deg_kernel<<<(E + 255) / 256, 256, 0, stream>>>(dst, cursor, E, nq, nr);
  dinv_bsum_pad_kernel<<<nb, 256, 0, stream>>>(cursor, dinv, bsum, x, xp, N, nq, nr);
  rowptr_vc0_kernel<<<nb, 256, 0, stream>>>(cursor, bsum, rows, cursor, N, E, nq, nr,
                                            W3, b3, lin_w, lin_b, W2, W2p, g, v, c0);
  fill_part_kernel<<<nchunk * 8, 256, 0, stream>>>(src, dst, cursor, colsrc, E, nq, nr);
  agg9_gemm1_kernel<<<nb, 256, 0, stream>>>(xp, dinv, rows, colsrc, W1, b1, hA, N);
  aggH_kernel<<<(N + 3) / 4, 256, 0, stream>>>(hA, rows, colsrc, g, N);
  gemmz_kernel<<<(N + 63) / 64, 256, 0, stream>>>(g, W2p, dinv, b2, v, zd, N);
  agg1_pool_kernel<<<nb, 256, 0, stream>>>(zd, dinv, rows, colsrc, batch, gsum, gcnt, N);
  final_kernel<<<1, 64, 0, stream>>>(gsum, gcnt, c0, out, G);
}

// Round 18
// 362.167 us; speedup vs baseline: 1.1402x; 1.0160x over previous
//
#include <hip/hip_runtime.h>
#include <math.h>

// Factorized GCN: A_hat = D^-1/2 (A+I) D^-1/2. All aggregations are
// prescale(rows by dinv) -> pure gather-sum over CSR cols -> postscale by dinv.
// CSR rows RANK-PERMUTED by class c=i&7 (fill's col lines owned by one XCD);
// node-indexed rows[i]=(rs,re). BF16 storage everywhere it's gathered/streamed:
// xp (prescaled x, 32B rows), hA (prescaled h1), g (aggregated S). fp32 acc.
// gemmz via bf16 MFMA (W2 pre-packed B-frags). aggH half-wave (r15/16 lesson).
// r18: agg9_gemm1 and agg1_pool were 391-block launches (~1.5 waves/SIMD) —
// latency-starved. Now 128 nodes/block, 2 threads/node, grid 782.

#define CHUNK 2048

using short8 = __attribute__((ext_vector_type(8))) short;
using floatx4 = __attribute__((ext_vector_type(4))) float;

__device__ __forceinline__ int rankof(int i, int nq, int nr) {
  int c = i & 7;
  return c * nq + min(c, nr) + (i >> 3);
}
__device__ __forceinline__ unsigned int f2bf(float f) {   // RNE
  unsigned int u = __float_as_uint(f);
  return ((u + 0x7fff + ((u >> 16) & 1)) >> 16);
}
__device__ __forceinline__ float bflo(unsigned int u) { return __uint_as_float(u << 16); }
__device__ __forceinline__ float bfhi(unsigned int u) { return __uint_as_float(u & 0xffff0000u); }

// ---------------- setup kernels ----------------

__global__ void deg_kernel(const int* __restrict__ dst, int* cnt_rank,
                           int E, int nq, int nr) {
  int e = blockIdx.x * blockDim.x + threadIdx.x;
  if (e < E) atomicAdd(&cnt_rank[rankof(dst[e], nq, nr)], 1);
}

// dinv + per-block rank-order sums -> bsum; xp = bf16(dinv_i * x_i), 16 bf16/row (32B)
__global__ void dinv_bsum_pad_kernel(const int* __restrict__ cnt_rank,
                                     float* __restrict__ dinv, int* bsum,
                                     const float* __restrict__ x,
                                     unsigned short* __restrict__ xp, int N, int nq, int nr) {
  __shared__ int s[256];
  int t = threadIdx.x;
  int gid = blockIdx.x * 256 + t;
  s[t] = (gid < N) ? cnt_rank[gid] : 0;     // scan basis: rank-order, coalesced
  if (gid < N) {
    int c = cnt_rank[rankof(gid, nq, nr)];  // this node's in-degree
    float di = 1.0f / sqrtf((float)c + 1.0f);
    dinv[gid] = di;
    const float* xr = x + (size_t)gid * 9;
    unsigned int w0 = f2bf(xr[0] * di) | (f2bf(xr[1] * di) << 16);
    unsigned int w1 = f2bf(xr[2] * di) | (f2bf(xr[3] * di) << 16);
    unsigned int w2 = f2bf(xr[4] * di) | (f2bf(xr[5] * di) << 16);
    unsigned int w3 = f2bf(xr[6] * di) | (f2bf(xr[7] * di) << 16);
    unsigned int w4 = f2bf(xr[8] * di);
    uint4* xo = (uint4*)(xp + (size_t)gid * 16);
    xo[0] = make_uint4(w0, w1, w2, w3);
    xo[1] = make_uint4(w4, 0u, 0u, 0u);
  }
  __syncthreads();
  for (int off = 128; off > 0; off >>= 1) {
    if (t < off) s[t] += s[t + off];
    __syncthreads();
  }
  if (t == 0) bsum[blockIdx.x] = s[0];
}

// Scan over RANK space -> rank-indexed cursor (fill) + NODE-indexed rows[i].
// Block 0: v = W3@lin_w, c0 = b3.lin_w + lin_b; zero g row N (gemmz pad row).
// Blocks 1..8: pack W2 -> bf16 B-fragment layout W2p[ntile][kstep][lane][8].
__global__ void rowptr_vc0_kernel(const int* __restrict__ indeg, const int* __restrict__ bsum,
                                  int2* __restrict__ rows, int* cursor, int N, int E,
                                  int nq, int nr,
                                  const float* __restrict__ W3, const float* __restrict__ b3,
                                  const float* __restrict__ lin_w, const float* __restrict__ lin_b,
                                  const float* __restrict__ W2, unsigned short* __restrict__ W2p,
                                  unsigned short* __restrict__ g,
                                  float* v, float* c0) {
  __shared__ int ps[256];
  __shared__ int s[256];
  int t = threadIdx.x;
  int pref = 0;
  for (int q = t; q < blockIdx.x; q += 256) pref += bsum[q];
  ps[t] = pref;
  __syncthreads();
  for (int off = 128; off > 0; off >>= 1) {
    if (t < off) ps[t] += ps[t + off];
    __syncthreads();
  }
  int base = ps[0];
  int r = blockIdx.x * 256 + t;
  int val = (r < N) ? indeg[r] : 0;
  s[t] = val;
  __syncthreads();
  for (int off = 1; off < 256; off <<= 1) {
    int x = (t >= off) ? s[t - off] : 0;
    __syncthreads();
    s[t] += x;
    __syncthreads();
  }
  int excl = s[t] - val + base;
  if (r < N) {
    cursor[r] = excl;                       // rank-indexed fill cursor
    int c = 0;                              // invert rank -> node id
#pragma unroll
    for (int cc = 1; cc < 8; ++cc) {
      int b = cc * nq + min(cc, nr);
      if (r >= b) c = cc;
    }
    int iinv = ((r - (c * nq + min(c, nr))) << 3) | c;
    rows[iinv] = make_int2(excl, excl + val);  // node-indexed (scattered, once)
  }
  if (blockIdx.x == 0) {
    if (t < 64) ((unsigned int*)g)[(size_t)N * 64 + t] = 0u;  // zero pad row N
    if (t < 128) {
      float sv = 0.0f;
      for (int c = 0; c < 128; ++c) sv = fmaf(W3[t * 128 + c], lin_w[c], sv);
      v[t] = sv;
    } else if (t == 128) {
      float sv = 0.0f;
      for (int c = 0; c < 128; ++c) sv = fmaf(b3[c], lin_w[c], sv);
      c0[0] = sv + lin_b[0];
    }
  } else if (blockIdx.x <= 8) {
    // B-frag pack: lane holds W2[k][n], n = ntile*16 + (lane&15),
    // k = kstep*32 + (lane>>4)*8 + j, j=0..7
    int ntile = blockIdx.x - 1;
    int kstep = t >> 6, lane = t & 63;
    int n = ntile * 16 + (lane & 15);
    int k0 = kstep * 32 + ((lane >> 4) & 3) * 8;
    unsigned int pk[4];
#pragma unroll
    for (int jj = 0; jj < 4; ++jj)
      pk[jj] = f2bf(W2[(size_t)(k0 + 2 * jj) * 128 + n])
             | (f2bf(W2[(size_t)(k0 + 2 * jj + 1) * 128 + n]) << 16);
    *(uint4*)(W2p + (size_t)(((ntile * 4 + kstep) * 64 + lane) * 8)) =
        make_uint4(pk[0], pk[1], pk[2], pk[3]);
  }
}

__global__ __launch_bounds__(256) void fill_part_kernel(const int* __restrict__ src,
                                                        const int* __restrict__ dst,
                                                        int* cursor, int* __restrict__ col,
                                                        int E, int nq, int nr) {
  int sub = blockIdx.x & 7;
  int base = (blockIdx.x >> 3) * CHUNK;
#pragma unroll
  for (int j = 0; j < CHUNK / 256; ++j) {
    int e = base + j * 256 + threadIdx.x;
    if (e < E) {
      int d = dst[e];
      if ((d & 7) == sub) {
        int p = atomicAdd(&cursor[rankof(d, nq, nr)], 1);
        col[p] = src[e];
      }
    }
  }
}

// ---------------- layer 1 fused: xa = dinv_i * sum(xp), hA = bf16(dinv_i * relu(xa@W1+b1)) ----------------
// 128 nodes/block, 2 threads/node (even/odd edge interleave), grid 2x: fixes
// the 391-block latency starvation. Shuffle-xor(1) combines the two partials.

__global__ __launch_bounds__(256) void agg9_gemm1_kernel(const unsigned short* __restrict__ xp,
    const float* __restrict__ dinv, const int2* __restrict__ rows,
    const int* __restrict__ col, const float* __restrict__ W1,
    const float* __restrict__ b1, unsigned short* __restrict__ hA, int N) {
  __shared__ float sW[9 * 128];
  __shared__ float sx[128 * 9];
  __shared__ float sdi[128];           // per-row dinv for the GEMV-phase prescale
  int tid = threadIdx.x;
  for (int q = tid; q < 9 * 128; q += 256) sW[q] = W1[q];
  int nl = tid >> 1;                   // node-local 0..127
  int sl = tid & 1;                    // edge slot (even/odd)
  int i = blockIdx.x * 128 + nl;
  float A[9], B[9];
#pragma unroll
  for (int f = 0; f < 9; ++f) { A[f] = 0.0f; B[f] = 0.0f; }
  float di = 0.0f;
  if (i < N) {
    di = dinv[i];
    if (sl == 0) {                     // self term counted once
      const unsigned short* xi = xp + (size_t)i * 16;
      uint4 s0 = *(const uint4*)xi;
      unsigned int s1 = *(const unsigned int*)(xi + 8);
      A[0] = bflo(s0.x); A[1] = bfhi(s0.x); A[2] = bflo(s0.y); A[3] = bfhi(s0.y);
      A[4] = bflo(s0.z); A[5] = bfhi(s0.z); A[6] = bflo(s0.w); A[7] = bfhi(s0.w);
      A[8] = bflo(s1);
    }
    int2 rw = rows[i];
    int re = rw.y;
    int e = rw.x + sl;
    for (; e + 2 < re; e += 4) {       // this thread: edges e, e+2 (stride-2 split)
      int c0 = __builtin_nontemporal_load(&col[e]);
      int c1 = __builtin_nontemporal_load(&col[e + 2]);
      const unsigned short* p0 = xp + (size_t)c0 * 16;
      const unsigned short* p1 = xp + (size_t)c1 * 16;
      uint4 q0 = *(const uint4*)p0;
      unsigned int t0 = *(const unsigned int*)(p0 + 8);
      uint4 q1 = *(const uint4*)p1;
      unsigned int t1 = *(const unsigned int*)(p1 + 8);
      A[0] += bflo(q0.x); A[1] += bfhi(q0.x); A[2] += bflo(q0.y); A[3] += bfhi(q0.y);
      A[4] += bflo(q0.z); A[5] += bfhi(q0.z); A[6] += bflo(q0.w); A[7] += bfhi(q0.w);
      A[8] += bflo(t0);
      B[0] += bflo(q1.x); B[1] += bfhi(q1.x); B[2] += bflo(q1.y); B[3] += bfhi(q1.y);
      B[4] += bflo(q1.z); B[5] += bfhi(q1.z); B[6] += bflo(q1.w); B[7] += bfhi(q1.w);
      B[8] += bflo(t1);
    }
    for (; e < re; e += 2) {
      int c0 = __builtin_nontemporal_load(&col[e]);
      const unsigned short* p0 = xp + (size_t)c0 * 16;
      uint4 q0 = *(const uint4*)p0;
      unsigned int t0 = *(const unsigned int*)(p0 + 8);
      A[0] += bflo(q0.x); A[1] += bfhi(q0.x); A[2] += bflo(q0.y); A[3] += bfhi(q0.y);
      A[4] += bflo(q0.z); A[5] += bfhi(q0.z); A[6] += bflo(q0.w); A[7] += bfhi(q0.w);
      A[8] += bflo(t0);
    }
  }
  // combine the two per-node partials across lane-pair (same wave)
#pragma unroll
  for (int f = 0; f < 9; ++f) {
    float tsum = A[f] + B[f];
    tsum += __shfl_xor(tsum, 1, 64);
    A[f] = tsum;
  }
  if (sl == 0) {
    float* so = sx + nl * 9;           // stride 9: worst 2-way alias (free)
#pragma unroll
    for (int f = 0; f < 9; ++f) so[f] = A[f] * di;
    sdi[nl] = di;
  }
  __syncthreads();
  // GEMV phase: thread owns TWO adjacent output columns -> one packed 4B store.
  int c2i = tid & 63, rsub = tid >> 6;   // 64 col-pairs x 4 row-slots
  float wA[9], wB[9];
#pragma unroll
  for (int f = 0; f < 9; ++f) {
    wA[f] = sW[f * 128 + 2 * c2i];
    wB[f] = sW[f * 128 + 2 * c2i + 1];
  }
  float biasA = b1[2 * c2i], biasB = b1[2 * c2i + 1];
  int base = blockIdx.x * 128;
  for (int j = 0; j < 32; ++j) {
    int rl = j * 4 + rsub;             // wave-uniform -> sx reads broadcast
    int row = base + rl;
    if (row >= N) break;               // wave-uniform break
    float sA = biasA, sB = biasB;
#pragma unroll
    for (int f = 0; f < 9; ++f) {
      float xv = sx[rl * 9 + f];
      sA = fmaf(xv, wA[f], sA);
      sB = fmaf(xv, wB[f], sB);
    }
    float d = sdi[rl];
    unsigned int pk = f2bf(fmaxf(sA, 0.0f) * d) | (f2bf(fmaxf(sB, 0.0f) * d) << 16);
    *(unsigned int*)(hA + (size_t)row * 128 + 2 * c2i) = pk;
  }
}

// ---------------- layer 2 aggregation: S = (A+I)-sum of prescaled-h1 rows ----------------
// Half-wave: 32 lanes x uint2 (8B) = one full 256B bf16 row; 8 edges/iter.
// [r16/r17: ~73 us, FETCH = 8 XCD x 25.6 MB compulsory floor]

__global__ __launch_bounds__(256) void aggH_kernel(const unsigned short* __restrict__ h,
    const int2* __restrict__ rows, const int* __restrict__ col,
    unsigned short* __restrict__ g, int N) {
  int wave = threadIdx.x >> 6;
  int lane = threadIdx.x & 63;
  int half = lane >> 5;                // each 32-lane half gathers one full row
  int l32  = lane & 31;
  int i = blockIdx.x * 4 + wave;
  if (i >= N) return;                  // wave-uniform exit
  uint2 sp = *((const uint2*)(h + (size_t)i * 128) + l32);
  float m = half ? 0.0f : 1.0f;        // self counted once (lower half)
  float4 a0 = make_float4(bflo(sp.x) * m, bfhi(sp.x) * m, bflo(sp.y) * m, bfhi(sp.y) * m);
  float4 a1 = make_float4(0.f, 0.f, 0.f, 0.f);
  float4 a2 = make_float4(0.f, 0.f, 0.f, 0.f);
  float4 a3 = make_float4(0.f, 0.f, 0.f, 0.f);
  int2 rw = rows[i];
  int rs = rw.x, re = rw.y;
  int e = rs;
  for (; e + 8 <= re; e += 8) {        // 8 edges/iter, 4 gathers in flight per half
    int c0 = __builtin_nontemporal_load(&col[e + half]);
    int c1 = __builtin_nontemporal_load(&col[e + 2 + half]);
    int c2 = __builtin_nontemporal_load(&col[e + 4 + half]);
    int c3 = __builtin_nontemporal_load(&col[e + 6 + half]);
    uint2 p0 = *((const uint2*)(h + (size_t)c0 * 128) + l32);
    uint2 p1 = *((const uint2*)(h + (size_t)c1 * 128) + l32);
    uint2 p2 = *((const uint2*)(h + (size_t)c2 * 128) + l32);
    uint2 p3 = *((const uint2*)(h + (size_t)c3 * 128) + l32);
    a0.x += bflo(p0.x); a0.y += bfhi(p0.x); a0.z += bflo(p0.y); a0.w += bfhi(p0.y);
    a1.x += bflo(p1.x); a1.y += bfhi(p1.x); a1.z += bflo(p1.y); a1.w += bfhi(p1.y);
    a2.x += bflo(p2.x); a2.y += bfhi(p2.x); a2.z += bflo(p2.y); a2.w += bfhi(p2.y);
    a3.x += bflo(p3.x); a3.y += bfhi(p3.x); a3.z += bflo(p3.y); a3.w += bfhi(p3.y);
  }
  if (e + 4 <= re) {
    int c0 = __builtin_nontemporal_load(&col[e + half]);
    int c1 = __builtin_nontemporal_load(&col[e + 2 + half]);
    uint2 p0 = *((const uint2*)(h + (size_t)c0 * 128) + l32);
    uint2 p1 = *((const uint2*)(h + (size_t)c1 * 128) + l32);
    a0.x += bflo(p0.x); a0.y += bfhi(p0.x); a0.z += bflo(p0.y); a0.w += bfhi(p0.y);
    a1.x += bflo(p1.x); a1.y += bfhi(p1.x); a1.z += bflo(p1.y); a1.w += bfhi(p1.y);
    e += 4;
  }
  if (e + 2 <= re) {
    int c0 = __builtin_nontemporal_load(&col[e + half]);
    uint2 p0 = *((const uint2*)(h + (size_t)c0 * 128) + l32);
    a2.x += bflo(p0.x); a2.y += bfhi(p0.x); a2.z += bflo(p0.y); a2.w += bfhi(p0.y);
    e += 2;
  }
  if (e < re) {                        // odd tail: both halves take 0.5 (exact)
    int c0 = __builtin_nontemporal_load(&col[e]);
    uint2 p0 = *((const uint2*)(h + (size_t)c0 * 128) + l32);
    a3.x = fmaf(bflo(p0.x), 0.5f, a3.x); a3.y = fmaf(bfhi(p0.x), 0.5f, a3.y);
    a3.z = fmaf(bflo(p0.y), 0.5f, a3.z); a3.w = fmaf(bfhi(p0.y), 0.5f, a3.w);
  }
  float4 a = make_float4((a0.x + a1.x) + (a2.x + a3.x), (a0.y + a1.y) + (a2.y + a3.y),
                         (a0.z + a1.z) + (a2.z + a3.z), (a0.w + a1.w) + (a2.w + a3.w));
  a.x += __shfl_down(a.x, 32, 64);     // combine halves -> lanes 0..31 hold full row
  a.y += __shfl_down(a.y, 32, 64);
  a.z += __shfl_down(a.z, 32, 64);
  a.w += __shfl_down(a.w, 32, 64);
  if (half == 0) {                     // lanes 0..31 pack bf16 -> 256B row store
    uint2 o;
    o.x = f2bf(a.x) | (f2bf(a.y) << 16);
    o.y = f2bf(a.z) | (f2bf(a.w) << 16);
    *((uint2*)(g + (size_t)i * 128) + l32) = o;
  }
}

// ---------------- fused layer-2/3 head via bf16 MFMA ----------------
// zd = dinv .* (relu(dinv.*(S@W2) + b2) @ v). LDS-free, barrier-free.

__global__ __launch_bounds__(256) void gemmz_kernel(const unsigned short* __restrict__ g,
    const unsigned short* __restrict__ W2p, const float* __restrict__ dinv,
    const float* __restrict__ b2, const float* __restrict__ v,
    float* __restrict__ zd, int N) {
  int wave = threadIdx.x >> 6, lane = threadIdx.x & 63;
  int rb16 = blockIdx.x * 64 + wave * 16;       // wave's 16-row window
  int m = lane & 15, quad = lane >> 4;
  int rowA = rb16 + m;
  const unsigned short* gp = g + (size_t)((rowA < N) ? rowA : N) * 128 + quad * 8;
  floatx4 acc[8];
#pragma unroll
  for (int t = 0; t < 8; ++t) acc[t] = (floatx4){0.f, 0.f, 0.f, 0.f};
#pragma unroll
  for (int ks = 0; ks < 4; ++ks) {
    short8 afrag = *(const short8*)(gp + ks * 32);
#pragma unroll
    for (int t = 0; t < 8; ++t) {
      short8 bfrag = *(const short8*)(W2p + (size_t)(((t * 4 + ks) * 64 + lane) * 8));
      acc[t] = __builtin_amdgcn_mfma_f32_16x16x32_bf16(afrag, bfrag, acc[t], 0, 0, 0);
    }
  }
  float b2c[8], vc[8];
#pragma unroll
  for (int t = 0; t < 8; ++t) {
    int ncol = t * 16 + m;
    b2c[t] = b2[ncol];
    vc[t] = v[ncol];
  }
#pragma unroll
  for (int reg = 0; reg < 4; ++reg) {
    int grow = rb16 + quad * 4 + reg;
    float dr = (grow < N) ? dinv[grow] : 0.0f;
    float p = 0.0f;
#pragma unroll
    for (int t = 0; t < 8; ++t)
      p += fmaxf(fmaf(dr, acc[t][reg], b2c[t]), 0.0f) * vc[t];
#pragma unroll
    for (int mk = 1; mk <= 8; mk <<= 1) p += __shfl_xor(p, mk, 64);  // over m (lane&15)
    if (m == 0 && grow < N) zd[grow] = dr * p;   // prescaled for layer-3
  }
}

// ---------------- layer 3 (scalar) aggregation + mean-pool binning ----------------
// 128 nodes/block, 2 threads/node (even/odd edges), grid 2x for latency hiding.

__global__ void agg1_pool_kernel(const float* __restrict__ zd, const float* __restrict__ dinv,
    const int2* __restrict__ rows, const int* __restrict__ col,
    const int* __restrict__ batch, float* gsum, float* gcnt, int N) {
  __shared__ float lsum[64];
  __shared__ float lcnt[64];
  int t = threadIdx.x;
  if (t < 64) { lsum[t] = 0.0f; lcnt[t] = 0.0f; }
  __syncthreads();
  int nl = t >> 1, sl = t & 1;
  int i = blockIdx.x * 128 + nl;
  float acc = 0.0f;
  if (i < N) {
    int2 rw = rows[i];
    int re = rw.y;
    if (sl == 0) acc = zd[i];          // self (weight 1 in prescaled domain)
    int e = rw.x + sl;
    for (; e + 2 < re; e += 4) {       // this thread: edges e, e+2
      float z0 = zd[col[e]], z1 = zd[col[e + 2]];
      acc += z0 + z1;
    }
    for (; e < re; e += 2) acc += zd[col[e]];
  }
  acc += __shfl_xor(acc, 1, 64);       // combine lane pair
  if (i < N && sl == 0) {
    acc *= dinv[i];
    int gidx = batch[i];
    atomicAdd(&lsum[gidx], acc);
    atomicAdd(&lcnt[gidx], 1.0f);
  }
  __syncthreads();
  if (t < 64) {
    if (lsum[t] != 0.0f) atomicAdd(&gsum[t], lsum[t]);
    if (lcnt[t] != 0.0f) atomicAdd(&gcnt[t], lcnt[t]);
  }
}

__global__ void final_kernel(const float* __restrict__ gsum, const float* __restrict__ gcnt,
                             const float* __restrict__ c0, float* out, int G) {
  int g = threadIdx.x;
  if (g < G) out[g] = gsum[g] / fmaxf(gcnt[g], 1.0f) + c0[0];
}

// ---------------- launch ----------------

extern "C" void kernel_launch(void* const* d_in, const int* in_sizes, int n_in,
                              void* d_out, int out_size, void* d_ws, size_t ws_size,
                              hipStream_t stream) {
  const float* x      = (const float*)d_in[0];
  const int*   eidx   = (const int*)d_in[1];
  const int*   batch  = (const int*)d_in[2];
  const float* W1     = (const float*)d_in[3];
  const float* b1     = (const float*)d_in[4];
  const float* W2     = (const float*)d_in[5];
  const float* b2     = (const float*)d_in[6];
  const float* W3     = (const float*)d_in[7];
  const float* b3     = (const float*)d_in[8];
  const float* lin_w  = (const float*)d_in[9];
  const float* lin_b  = (const float*)d_in[10];
  float* out = (float*)d_out;

  int N = in_sizes[0] / 9;
  int E = in_sizes[1] / 2;
  int G = out_size;
  const int* src = eidx;
  const int* dst = eidx + E;
  int nq = N >> 3, nr = N & 7;         // rank(i) = (i&7)*nq + min(i&7,nr) + (i>>3)

  char* w = (char*)d_ws;
  size_t off = 0;
  auto alloc = [&](size_t bytes) -> void* {
    void* p = w + off;
    off += bytes;
    off = (off + 255) & ~(size_t)255;
    return p;
  };

  int nb = (N + 255) / 256;
  int nb2 = (N + 127) / 128;
  int nchunk = (E + CHUNK - 1) / CHUNK;
  // zero-init region (one memset): cursor (rank-space degree counts), gsum, gcnt
  int*   cursor = (int*)  alloc((size_t)N * 4);        // counts, then fill cursor (rank-indexed)
  float* gsum   = (float*)alloc(64 * 4);
  float* gcnt   = (float*)alloc(64 * 4);
  size_t zspan = off;
  float* dinv   = (float*)alloc((size_t)N * 4);
  int2*  rows   = (int2*) alloc((size_t)N * 8);        // node-indexed (rs,re)
  int*   bsum   = (int*)  alloc((size_t)nb * 4);
  int*   colsrc = (int*)  alloc((size_t)E * 4);        // CSR cols, class-contiguous regions
  unsigned short* hA  = (unsigned short*)alloc((size_t)N * 128 * 2);        // prescaled h1, BF16
  unsigned short* g   = (unsigned short*)alloc((size_t)(N + 1) * 128 * 2);  // xp (Nx16 bf16) first, then S BF16 (+pad row N)
  unsigned short* W2p = (unsigned short*)alloc(8 * 4 * 64 * 8 * 2);         // MFMA B-frag packed W2
  float* zd     = (float*)alloc((size_t)N * 4);
  float* v      = (float*)alloc(128 * 4);
  float* c0     = (float*)alloc(4);
  unsigned short* xp = g;                              // alias: dead before aggH writes g

  hipMemsetAsync(d_ws, 0, zspan, stream);
  deg_kernel<<<(E + 255) / 256, 256, 0, stream>>>(dst, cursor, E, nq, nr);
  dinv_bsum_pad_kernel<<<nb, 256, 0, stream>>>(cursor, dinv, bsum, x, xp, N, nq, nr);
  rowptr_vc0_kernel<<<nb, 256, 0, stream>>>(cursor, bsum, rows, cursor, N, E, nq, nr,
                                            W3, b3, lin_w, lin_b, W2, W2p, g, v, c0);
  fill_part_kernel<<<nchunk * 8, 256, 0, stream>>>(src, dst, cursor, colsrc, E, nq, nr);
  agg9_gemm1_kernel<<<nb2, 256, 0, stream>>>(xp, dinv, rows, colsrc, W1, b1, hA, N);
  aggH_kernel<<<(N + 3) / 4, 256, 0, stream>>>(hA, rows, colsrc, g, N);
  gemmz_kernel<<<(N + 63) / 64, 256, 0, stream>>>(g, W2p, dinv, b2, v, zd, N);
  agg1_pool_kernel<<<nb2, 256, 0, stream>>>(zd, dinv, rows, colsrc, batch, gsum, gcnt, N);
  final_kernel<<<1, 64, 0, stream>>>(gsum, gcnt, c0, out, G);
}